// Round 12
// baseline (1130.439 us; speedup 1.0000x reference)
//
#include <hip/hip_runtime.h>
#include <hip/hip_bf16.h>

// RNNLayer: B=64, T=512, D_IN=D_H=D_OUT=1024.
// h_{t+1} = A h_t + u_t  (A = Wrh, u_t = x_t@Wxh^T + bh);  o_t = x_t@Wxo^T + h_t@Wro^T + bo
// Scan decomposition (sequential depth 511 -> 31 + 15):
//   tree:  v1=A u+u', v2=A2 v1+v1', v3=A4 v2+v2', v4=A8 v3+v3'  (plain GEMMs)
//   chain: h_{16(k+1)} = A16 h_{16k} + v4_k       (31 flag-sync steps, 64 WGs)
//   fill:  h_{16k+tau+1} = A h_{16k+tau} + u      (15 flag-sync steps, 256 WGs, nch=8)
// r11 -> r12: (1) gemm1 BK 32->64 (halves barrier count, LDS 32 KB);
// (2) k_chain chunk pipelining: double-buffered hbuf, next chunk's 9 memops
// (8 gload_lds + 1 xv) issued before current chunk's compute, counted vmcnt(9).
// nch=1 (chain mode) degenerates to the r11-verified sequence.

typedef _Float16 f16;
typedef _Float16 f16x8 __attribute__((ext_vector_type(8)));
typedef _Float16 f16x4 __attribute__((ext_vector_type(4)));
typedef float f32x4 __attribute__((ext_vector_type(4)));
typedef int i32x4 __attribute__((ext_vector_type(4)));

#define T_LEN 512
#define BATCH 64
#define M_TOT (BATCH * T_LEN)   // 32768

// slab layout (per t): [bg 4][cblk 128][b 16][8] f16 = 65536 elems (128 KB)

// ---------- prep: stacked fp16 weights ----------
__global__ void k_prep_w(const float* __restrict__ Wh, const float* __restrict__ Wo,
                         f16* __restrict__ Wx, f16* __restrict__ Wr) {
    int n = blockIdx.x;              // 0..2047
    int t4 = threadIdx.x * 4;        // 0..1020
    const float* src = (n < 1024) ? (Wh + (size_t)n * 2048)
                                  : (Wo + (size_t)(n - 1024) * 2048);
    float4 a = *reinterpret_cast<const float4*>(src + t4);
    float4 b = *reinterpret_cast<const float4*>(src + 1024 + t4);
    f16x4 va, vb;
    va[0]=(f16)a.x; va[1]=(f16)a.y; va[2]=(f16)a.z; va[3]=(f16)a.w;
    vb[0]=(f16)b.x; vb[1]=(f16)b.y; vb[2]=(f16)b.z; vb[3]=(f16)b.w;
    *reinterpret_cast<f16x4*>(Wx + (size_t)n*1024 + t4) = va;
    *reinterpret_cast<f16x4*>(Wr + (size_t)n*1024 + t4) = vb;
}

// ---------- prep: X f32 -> Xf f16 row-major [32768][1024] ----------
__global__ void k_prep_x(const float* __restrict__ X, f16* __restrict__ Xf) {
    size_t i = ((size_t)blockIdx.x * 256 + threadIdx.x) * 8;   // grid 16384 x 256
    float4 a = *reinterpret_cast<const float4*>(X + i);
    float4 b = *reinterpret_cast<const float4*>(X + i + 4);
    f16x8 v;
    v[0]=(f16)a.x; v[1]=(f16)a.y; v[2]=(f16)a.z; v[3]=(f16)a.w;
    v[4]=(f16)b.x; v[5]=(f16)b.y; v[6]=(f16)b.z; v[7]=(f16)b.w;
    *reinterpret_cast<f16x8*>(Xf + i) = v;
}

// ---------- init: Hs[0] from H0 (packed layout) ----------
__global__ void k_init_h(const float* __restrict__ H0, f16* __restrict__ Hs) {
    int tid = blockIdx.x * 256 + threadIdx.x;   // 8192
    int b = tid >> 7, kb = tid & 127;
    float4 x0 = *reinterpret_cast<const float4*>(H0 + (size_t)b*1024 + kb*8);
    float4 x1 = *reinterpret_cast<const float4*>(H0 + (size_t)b*1024 + kb*8 + 4);
    f16x8 v;
    v[0]=(f16)x0.x; v[1]=(f16)x0.y; v[2]=(f16)x0.z; v[3]=(f16)x0.w;
    v[4]=(f16)x1.x; v[5]=(f16)x1.y; v[6]=(f16)x1.z; v[7]=(f16)x1.w;
    size_t idx = (size_t)(b >> 4)*16384 + (size_t)kb*128 + (size_t)(b & 15)*8;
    *reinterpret_cast<f16x8*>(Hs + idx) = v;
}

__global__ void k_zero_flags(unsigned int* __restrict__ flags) {
    flags[blockIdx.x * 256 + threadIdx.x] = 0;   // 2048 u32 (256 logical flags, 32B apart)
}

// ---------- phase 1: input projection GEMM (m97 structure, BK=64) ----------
// A = Xf f16 [32768][1024] (rows m = b*512+t), B = Wx f16 [2048][1024]
// Staged via global_load_lds(16B) into linear LDS [128][64] f16 (16 KB each).
__global__ __launch_bounds__(256) void k_gemm1(
    const f16* __restrict__ Af, const f16* __restrict__ Bm,
    const float* __restrict__ bh, const float* __restrict__ bo,
    f16* __restrict__ Xh, float* __restrict__ Out)
{
    __shared__ f16 As[128*64];   // 16 KB, linear row-major [128][64]
    __shared__ f16 Bs[128*64];   // 16 KB
    int m0 = blockIdx.x * 128;
    int n0 = blockIdx.y * 128;
    int t = threadIdx.x;
    int l = t & 63, w = t >> 6;
    int wm = w >> 1, wn = w & 1;
    int lm = l & 15, lh = l >> 4;

    f32x4 acc[4][4];
    #pragma unroll
    for (int i = 0; i < 4; i++)
        #pragma unroll
        for (int j = 0; j < 4; j++) acc[i][j] = (f32x4){0.f,0.f,0.f,0.f};

    // 128-B rows: one inst = 64 lanes x 16 B = 8 rows; 4 insts = wave's 32 rows
    const size_t lgo = (size_t)(l >> 3) * 2048 + (size_t)(l & 7) * 16;

    for (int kt = 0; kt < 16; ++kt) {
        __syncthreads();   // prior frag reads done before overwrite
        {
            const char* ga = (const char*)(Af + (size_t)(m0 + w*32) * 1024 + kt*64);
            const char* gb = (const char*)(Bm + (size_t)(n0 + w*32) * 1024 + kt*64);
            char* la = (char*)As + w * 4096;
            char* lb = (char*)Bs + w * 4096;
            #pragma unroll
            for (int j = 0; j < 4; ++j) {
                __builtin_amdgcn_global_load_lds(
                    (const __attribute__((address_space(1))) void*)(ga + (size_t)j*16384 + lgo),
                    (__attribute__((address_space(3))) void*)(la + j*1024), 16, 0, 0);
                __builtin_amdgcn_global_load_lds(
                    (const __attribute__((address_space(1))) void*)(gb + (size_t)j*16384 + lgo),
                    (__attribute__((address_space(3))) void*)(lb + j*1024), 16, 0, 0);
            }
        }
        asm volatile("s_waitcnt vmcnt(0)" ::: "memory");
        __syncthreads();

        #pragma unroll
        for (int kh = 0; kh < 2; ++kh) {
            f16x8 af[4], bf[4];
            #pragma unroll
            for (int i = 0; i < 4; i++)
                af[i] = *reinterpret_cast<const f16x8*>(As + (64*wm + 16*i + lm)*64 + kh*32 + 8*lh);
            #pragma unroll
            for (int j = 0; j < 4; j++)
                bf[j] = *reinterpret_cast<const f16x8*>(Bs + (64*wn + 16*j + lm)*64 + kh*32 + 8*lh);
            #pragma unroll
            for (int i = 0; i < 4; i++)
                #pragma unroll
                for (int j = 0; j < 4; j++)
                    acc[i][j] = __builtin_amdgcn_mfma_f32_16x16x32_f16(af[i], bf[j], acc[i][j], 0, 0, 0);
        }
    }

    int r0 = lh * 4;
    bool isH = (n0 < 1024);
    #pragma unroll
    for (int i = 0; i < 4; i++)
        #pragma unroll
        for (int j = 0; j < 4; j++) {
            int gmb = m0 + 64*wm + 16*i + r0;
            int gn  = n0 + 64*wn + 16*j + lm;
            #pragma unroll
            for (int r = 0; r < 4; r++) {
                float v = acc[i][j][r];
                int gm = gmb + r;                 // m = b*512 + t
                if (isH) {
                    int tt = gm & 511, bb = gm >> 9;
                    size_t idx = (size_t)tt*65536 + (size_t)(bb>>4)*16384
                               + (size_t)(gn>>3)*128 + (size_t)(bb&15)*8 + (gn&7);
                    Xh[idx] = (f16)(v + bh[gn]);
                } else {
                    Out[(size_t)gm*1024 + (gn - 1024)] = v + bo[gn - 1024];
                }
            }
        }
}

// ---------- matrix squaring: Pout = P*P (B transposed in-LDS; verified r9) ----------
__global__ __launch_bounds__(256) void k_sq(const f16* __restrict__ P, f16* __restrict__ Pout)
{
    __shared__ f16 As[128][40];
    __shared__ f16 Bs[128][40];
    int m0 = blockIdx.x * 128, n0 = blockIdx.y * 128;
    int t = threadIdx.x;
    int l = t & 63, wid = t >> 6;
    int wm = wid >> 1, wn = wid & 1;
    int lm = l & 15, lh = l >> 4;

    f32x4 acc[4][4];
    #pragma unroll
    for (int i = 0; i < 4; i++)
        #pragma unroll
        for (int j = 0; j < 4; j++) acc[i][j] = (f32x4){0.f,0.f,0.f,0.f};

    for (int kt = 0; kt < 32; ++kt) {
        __syncthreads();
        #pragma unroll
        for (int c = t; c < 512; c += 256) {       // A rows m, k-contig
            int row = c >> 2, q = c & 3;
            *reinterpret_cast<float4*>(&As[row][q*8]) =
                *reinterpret_cast<const float4*>(P + (size_t)(m0+row)*1024 + kt*32 + q*8);
        }
        #pragma unroll
        for (int c = t; c < 512; c += 256) {       // Bs[n][k] = P[k][n0+n]
            int r = c >> 4, q = c & 15;
            f16x8 v = *reinterpret_cast<const f16x8*>(P + (size_t)(kt*32 + r)*1024 + n0 + q*8);
            #pragma unroll
            for (int e = 0; e < 8; ++e) Bs[q*8+e][r] = v[e];
        }
        __syncthreads();

        f16x8 af[4], bf[4];
        #pragma unroll
        for (int i = 0; i < 4; i++)
            af[i] = *reinterpret_cast<const f16x8*>(&As[64*wm + 16*i + lm][8*lh]);
        #pragma unroll
        for (int j = 0; j < 4; j++)
            bf[j] = *reinterpret_cast<const f16x8*>(&Bs[64*wn + 16*j + lm][8*lh]);
        #pragma unroll
        for (int i = 0; i < 4; i++)
            #pragma unroll
            for (int j = 0; j < 4; j++)
                acc[i][j] = __builtin_amdgcn_mfma_f32_16x16x32_f16(af[i], bf[j], acc[i][j], 0, 0, 0);
    }

    int r0 = lh * 4;
    #pragma unroll
    for (int i = 0; i < 4; i++)
        #pragma unroll
        for (int j = 0; j < 4; j++) {
            int gmb = m0 + 64*wm + 16*i + r0;
            int gn  = n0 + 64*wn + 16*j + lm;
            #pragma unroll
            for (int r = 0; r < 4; r++)
                Pout[(size_t)(gmb+r)*1024 + gn] = (f16)acc[i][j][r];
        }
}

// ---------- v-level GEMM: Dst[k] = M * Src[f(2k)] + Src[f(2k+1)] (verified r11) ----------
__global__ __launch_bounds__(256) void k_vlevel(
    const f16* __restrict__ M, const f16* __restrict__ Src, f16* __restrict__ Dst,
    int srcOff, int srcStep, int dstOff, int dstStep)
{
    __shared__ f16 As[4096];   // 8 KB
    __shared__ f16 Bs[128*32]; // 8 KB, [row][32] linear
    int m0 = blockIdx.x * 128;          // rows m = k*64 + b
    int n0 = blockIdx.y * 128;
    int t = threadIdx.x;
    int l = t & 63, w = t >> 6;
    int wm = w >> 1, wn = w & 1;
    int lm = l & 15, lh = l >> 4;

    f32x4 acc[4][4];
    #pragma unroll
    for (int i = 0; i < 4; i++)
        #pragma unroll
        for (int j = 0; j < 4; j++) acc[i][j] = (f32x4){0.f,0.f,0.f,0.f};

    const size_t lgo = (size_t)(l >> 2) * 2048 + (size_t)(l & 3) * 16;   // B (2048 B/row)
    const int kd0 = m0 >> 6;

    for (int kt = 0; kt < 32; ++kt) {
        __syncthreads();
        {
            #pragma unroll
            for (int j = 0; j < 2; ++j) {
                int ch  = w*2 + j;               // 0..7
                int kdl = ch >> 2, bgc = ch & 3;
                size_t slab = (size_t)(srcOff + srcStep * (2*(kd0 + kdl)));
                const char* gsrc = (const char*)(Src + slab*65536
                                    + (size_t)bgc*16384 + (size_t)kt*512) + (size_t)l*16;
                __builtin_amdgcn_global_load_lds(
                    (const __attribute__((address_space(1))) void*)gsrc,
                    (__attribute__((address_space(3))) void*)((char*)As + ch*1024), 16, 0, 0);
            }
            const char* gb = (const char*)(M + (size_t)(n0 + w*32) * 1024 + kt*32);
            char* lb = (char*)Bs + w * 2048;
            #pragma unroll
            for (int j = 0; j < 2; ++j)
                __builtin_amdgcn_global_load_lds(
                    (const __attribute__((address_space(1))) void*)(gb + (size_t)j*32768 + lgo),
                    (__attribute__((address_space(3))) void*)(lb + j*1024), 16, 0, 0);
        }
        asm volatile("s_waitcnt vmcnt(0)" ::: "memory");
        __syncthreads();

        f16x8 af[4], bf[4];
        #pragma unroll
        for (int i = 0; i < 4; i++)
            af[i] = *reinterpret_cast<const f16x8*>(As + wm*2048 + i*512 + lh*128 + lm*8);
        #pragma unroll
        for (int j = 0; j < 4; j++)
            bf[j] = *reinterpret_cast<const f16x8*>(Bs + (64*wn + 16*j + lm)*32 + 8*lh);
        #pragma unroll
        for (int i = 0; i < 4; i++)
            #pragma unroll
            for (int j = 0; j < 4; j++)
                acc[i][j] = __builtin_amdgcn_mfma_f32_16x16x32_f16(af[i], bf[j], acc[i][j], 0, 0, 0);
    }

    int r0 = lh * 4;
    #pragma unroll
    for (int i = 0; i < 4; i++)
        #pragma unroll
        for (int j = 0; j < 4; j++) {
            int gmb = m0 + 64*wm + 16*i + r0;
            int gn  = n0 + 64*wn + 16*j + lm;
            #pragma unroll
            for (int r = 0; r < 4; r++) {
                int gm = gmb + r;
                int kd = gm >> 6, bb = gm & 63;
                size_t pidx = (size_t)(bb>>4)*16384 + (size_t)(gn>>3)*128
                            + (size_t)(bb&15)*8 + (gn&7);
                size_t aslab = (size_t)(srcOff + srcStep * (2*kd + 1));
                float add = (float)Src[aslab*65536 + pidx];
                size_t dslab = (size_t)(dstOff + dstStep * kd);
                Dst[dslab*65536 + pidx] = (f16)(acc[i][j][r] + add);
            }
        }
}

// ---------- flag-sync recurrence kernel (r9/r11-verified protocol; r12: chunk pipeline) ----------
// mode 1 (CHAIN): 64 WGs, nch=1. step t: Hs[16t] -> Hs[16t+16], u = Hs[16t+8] (v4).
//   decode: r=wg&7, s=wg>>3: g=bg=r>>1, cg=((r&1)<<3)|s, p=0  (group on XCD pair)
// mode 2 (FILL): 256 WGs, nch=8. step t: Hs[c*16+t] -> +1, u = Xh[c*16+t], c=p*8+i.
//   decode: r=wg&7, s=wg>>3: g=2r+(s>>4), cg=s&15, p=g>>2, bg=g&3 (group on one XCD)
// Pipeline: chunk i+1's 9 memops (8 gload_lds + 1 xv) issued before chunk i's
// compute; counted vmcnt(9) -> buf[i]'s ops (oldest) complete. nch=1 degenerates.
__global__ void __launch_bounds__(256) __attribute__((amdgpu_waves_per_eu(1, 1)))
k_chain(
    const f16* __restrict__ W,        // [1024][1024] row-major (A or A16)
    const f16* __restrict__ U,        // u base (slab-packed)
    f16* __restrict__ Hs,
    unsigned int* __restrict__ flags,
    int nstep, int mode, int nch)
{
    int wg = blockIdx.x;
    int r_ = wg & 7, s_ = wg >> 3;
    int g, cg, p, bg;
    if (mode == 1) { g = r_ >> 1; cg = ((r_ & 1) << 3) | s_; p = 0;       bg = g;     }
    else           { g = 2*r_ + (s_ >> 4); cg = s_ & 15;     p = g >> 2;  bg = g & 3; }
    int w  = threadIdx.x >> 6;
    int l  = threadIdx.x & 63;
    int lm = l & 15, lh = l >> 4;
    int ccol = cg * 64 + w * 16 + lm;

    __shared__ f16 hbuf[2][16384];      // 64 KB double-buffered h slab
    __shared__ float lt[4][16][17];

    // register-resident recurrent weights: 16 cols x K=1024 = 128 VGPRs/lane.
    f16x8 bw[32];
    #pragma unroll
    for (int kt = 0; kt < 32; ++kt)
        bw[kt] = *reinterpret_cast<const f16x8*>(W + (size_t)ccol * 1024 + kt*32 + lh*8);
    #pragma unroll
    for (int kt = 0; kt < 32; ++kt)
        asm volatile("" : "+v"(bw[kt]));

    const int flagBase = g * 16;
    int b_ep = l & 15, cb_ep = l >> 4;
    int cblk = cg*8 + w*2 + cb_ep;

    for (int t = 0; t < nstep; ++t) {
        if (t > 0) {
            if (threadIdx.x < 16) {
                unsigned int tgt = (unsigned int)t;
                const unsigned int* fp = &flags[(flagBase + (int)threadIdx.x) * 8];
                while (__hip_atomic_load(fp, __ATOMIC_RELAXED, __HIP_MEMORY_SCOPE_AGENT) < tgt)
                    __builtin_amdgcn_s_sleep(1);
            }
            __syncthreads();
            asm volatile("" ::: "memory");
        }

        // slab indices for chunk i
        auto slabs = [&](int i, size_t& rS, size_t& wS, size_t& uS) {
            if (mode == 1) { rS = (size_t)(16*t); wS = rS + 16; uS = rS + 8; }
            else { int c = p*nch + i; rS = (size_t)(c*16 + t); wS = rS + 1; uS = rS; }
        };
        auto STAGE = [&](size_t rS, int buf) {
            const char* gsrc = (const char*)Hs + (rS*65536 + (size_t)bg*16384)*2
                             + (size_t)w*8192 + (size_t)l*16;
            char* ldst = (char*)&hbuf[buf][0] + (size_t)w*8192;
            #pragma unroll
            for (int q = 0; q < 8; ++q)
                __builtin_amdgcn_global_load_lds(
                    (const __attribute__((address_space(1))) void*)(gsrc + q*1024),
                    (__attribute__((address_space(3))) void*)(ldst + q*1024),
                    16, 0, 0);
        };
        auto XV = [&](size_t uS) -> f16x8 {
            f16x8 v = {};
            if (l < 32)
                v = *reinterpret_cast<const f16x8*>(
                    U + uS*65536 + (size_t)bg*16384 + (size_t)cblk*128 + b_ep*8);
            return v;
        };

        // prologue: chunk 0 -> buf 0 (9 memops/wave)
        f16x8 xv0, xv1;
        {
            size_t rS, wS, uS; slabs(0, rS, wS, uS);
            STAGE(rS, 0);
            xv0 = XV(uS);
        }

        for (int i = 0; i < nch; ++i) {
            int nxt = i + 1;
            if (nxt < nch) {
                size_t rS, wS, uS; slabs(nxt, rS, wS, uS);
                STAGE(rS, nxt & 1);
                if (nxt & 1) xv1 = XV(uS); else xv0 = XV(uS);
                asm volatile("s_waitcnt vmcnt(9)" ::: "memory");
            } else {
                asm volatile("s_waitcnt vmcnt(0)" ::: "memory");
            }
            __syncthreads();

            const f16* cbuf = &hbuf[i & 1][0];
            f32x4 a0 = (f32x4){0.f,0.f,0.f,0.f};
            f32x4 a1 = (f32x4){0.f,0.f,0.f,0.f};
            #pragma unroll
            for (int kt = 0; kt < 32; ++kt) {
                f16x8 af = *reinterpret_cast<const f16x8*>(&cbuf[(size_t)(kt*4 + lh)*128 + lm*8]);
                if (kt & 1) a1 = __builtin_amdgcn_mfma_f32_16x16x32_f16(af, bw[kt], a1, 0, 0, 0);
                else        a0 = __builtin_amdgcn_mfma_f32_16x16x32_f16(af, bw[kt], a0, 0, 0, 0);
            }
            f32x4 acc = a0 + a1;

            #pragma unroll
            for (int r = 0; r < 4; ++r)
                lt[w][lh*4 + r][lm] = acc[r];
            // wave-private RAW through LDS (compiler inserts lgkmcnt)

            if (l < 32) {
                f16x8 xvc = (i & 1) ? xv1 : xv0;
                size_t rS, wS, uS; slabs(i, rS, wS, uS);
                f16x8 hv;
                #pragma unroll
                for (int e = 0; e < 8; ++e)
                    hv[e] = (f16)(lt[w][b_ep][cb_ep*8 + e] + (float)xvc[e]);
                f16* dst = Hs + wS*65536 + (size_t)bg*16384 + (size_t)cblk*128 + b_ep*8;
                i32x4 iv = __builtin_bit_cast(i32x4, hv);
                asm volatile("global_store_dwordx4 %0, %1, off sc0 sc1"
                             :: "v"(dst), "v"(iv) : "memory");
            }
            __syncthreads();   // all waves done reading buf[i&1] before it is restaged
        }

        asm volatile("s_waitcnt vmcnt(0)" ::: "memory");
        __syncthreads();
        if (threadIdx.x == 0) {
            __builtin_amdgcn_fence(__ATOMIC_RELEASE, "agent");
            __hip_atomic_store(&flags[(flagBase + cg)*8], (unsigned int)(t+1),
                               __ATOMIC_RELAXED, __HIP_MEMORY_SCOPE_AGENT);
        }
    }
}

// ---------- phase 3: output GEMM  Out += Hs @ Wro^T (verified r11) ----------
__global__ __launch_bounds__(256) void k_gemm2(
    const f16* __restrict__ Hs, const f16* __restrict__ Bm, float* __restrict__ Out)
{
    __shared__ f16 As[4096];   // 8 KB: [ttloc2][bg4][kblk4][b16][e8]
    __shared__ f16 Bs[128*32]; // 8 KB
    int m0 = blockIdx.x * 128;          // m' = t*64 + b
    int n0 = blockIdx.y * 128;
    int t = threadIdx.x;
    int l = t & 63, w = t >> 6;
    int wm = w >> 1, wn = w & 1;
    int lm = l & 15, lh = l >> 4;

    f32x4 acc[4][4];
    #pragma unroll
    for (int i = 0; i < 4; i++)
        #pragma unroll
        for (int j = 0; j < 4; j++) acc[i][j] = (f32x4){0.f,0.f,0.f,0.f};

    const size_t lgo = (size_t)(l >> 2) * 2048 + (size_t)(l & 3) * 16;
    const int tt0 = m0 >> 6;

    for (int kt = 0; kt < 32; ++kt) {
        __syncthreads();
        {
            #pragma unroll
            for (int j = 0; j < 2; ++j) {
                int ch  = w*2 + j;               // 0..7
                int ttl = ch >> 2, bgc = ch & 3;
                const char* gsrc = (const char*)(Hs + (size_t)(tt0 + ttl)*65536
                                    + (size_t)bgc*16384 + (size_t)kt*512) + (size_t)l*16;
                __builtin_amdgcn_global_load_lds(
                    (const __attribute__((address_space(1))) void*)gsrc,
                    (__attribute__((address_space(3))) void*)((char*)As + ch*1024), 16, 0, 0);
            }
            const char* gb = (const char*)(Bm + (size_t)(n0 + w*32) * 1024 + kt*32);
            char* lb = (char*)Bs + w * 2048;
            #pragma unroll
            for (int j = 0; j < 2; ++j)
                __builtin_amdgcn_global_load_lds(
                    (const __attribute__((address_space(1))) void*)(gb + (size_t)j*32768 + lgo),
                    (__attribute__((address_space(3))) void*)(lb + j*1024), 16, 0, 0);
        }
        asm volatile("s_waitcnt vmcnt(0)" ::: "memory");
        __syncthreads();

        f16x8 af[4], bf[4];
        #pragma unroll
        for (int i = 0; i < 4; i++)
            af[i] = *reinterpret_cast<const f16x8*>(As + wm*2048 + i*512 + lh*128 + lm*8);
        #pragma unroll
        for (int j = 0; j < 4; j++)
            bf[j] = *reinterpret_cast<const f16x8*>(Bs + (64*wn + 16*j + lm)*32 + 8*lh);
        #pragma unroll
        for (int i = 0; i < 4; i++)
            #pragma unroll
            for (int j = 0; j < 4; j++)
                acc[i][j] = __builtin_amdgcn_mfma_f32_16x16x32_f16(af[i], bf[j], acc[i][j], 0, 0, 0);
    }

    int r0 = lh * 4;
    #pragma unroll
    for (int i = 0; i < 4; i++)
        #pragma unroll
        for (int j = 0; j < 4; j++) {
            int gmb = m0 + 64*wm + 16*i + r0;
            int gn  = n0 + 64*wn + 16*j + lm;
            #pragma unroll
            for (int r = 0; r < 4; r++) {
                int gm = gmb + r;               // m' = t*64 + b
                int bb = gm & 63, tt = gm >> 6;
                size_t o = ((size_t)bb*512 + tt)*1024 + gn;
                Out[o] += acc[i][j][r];
            }
        }
}

// ---------- workspace layout (bytes) — 136.07 MB total ----------
// [0, 4M)      Wx (gemm1); afterwards Pa @0, Pb @2M (A-power ping-pong)
// [4M, 8M)     Wr  (rows 0..1023 = A = Wrh, rows 1024..2047 = Wro)
// [8M, 72M)    Xh  [512 slabs]
// [72M, 136M)  Hs  [512 slabs]; ALSO Xf f16 [32768][1024] pre-gemm1 (dead after);
//              then V1 -> slabs 1..256, V2 -> odd 257.., V3 -> 2+4m, V4 -> 16c+8
// [136M, +8K)  flags u32[2048] (256 logical flags, 32B stride)

extern "C" void kernel_launch(void* const* d_in, const int* in_sizes, int n_in,
                              void* d_out, int out_size, void* d_ws, size_t ws_size,
                              hipStream_t stream) {
    const float* X  = (const float*)d_in[0];
    const float* H0 = (const float*)d_in[1];
    const float* Wh = (const float*)d_in[2];
    const float* bh = (const float*)d_in[3];
    const float* Wo = (const float*)d_in[4];
    const float* bo = (const float*)d_in[5];
    float* Out = (float*)d_out;

    char* ws = (char*)d_ws;
    f16* Wx = (f16*)(ws);
    f16* Pa = (f16*)(ws);                               // aliases Wx (dead after gemm1)
    f16* Pb = (f16*)(ws + (size_t)2*1024*1024);
    f16* Wr = (f16*)(ws + (size_t)4*1024*1024);
    f16* Xh = (f16*)(ws + (size_t)8*1024*1024);
    f16* Hs = (f16*)(ws + (size_t)8*1024*1024 + (size_t)M_TOT*1024*2);
    f16* Xf = Hs;                                       // aliases Hs (dead until after gemm1)
    unsigned int* flags = (unsigned int*)(ws + (size_t)8*1024*1024 + (size_t)2*M_TOT*1024*2);

    hipLaunchKernelGGL(k_prep_w, dim3(2048), dim3(256), 0, stream, Wh, Wo, Wx, Wr);
    hipLaunchKernelGGL(k_prep_x, dim3(16384), dim3(256), 0, stream, X, Xf);
    hipLaunchKernelGGL(k_gemm1, dim3(256, 16), dim3(256), 0, stream, Xf, Wx, bh, bo, Xh, Out);
    hipLaunchKernelGGL(k_init_h, dim3(32), dim3(256), 0, stream, H0, Hs);   // after gemm1: Xf dead

    // A-power / v-level interleave (each value consumed before overwrite)
    hipLaunchKernelGGL(k_sq, dim3(8,8), dim3(256), 0, stream, Wr, Pa);                   // Pa = A2
    hipLaunchKernelGGL(k_vlevel, dim3(128,8), dim3(256), 0, stream, Wr, Xh, Hs, 0,1, 1,1);     // V1
    hipLaunchKernelGGL(k_vlevel, dim3(64,8),  dim3(256), 0, stream, Pa, Hs, Hs, 1,1, 257,2);   // V2
    hipLaunchKernelGGL(k_sq, dim3(8,8), dim3(256), 0, stream, Pa, Pb);                   // Pb = A4
    hipLaunchKernelGGL(k_vlevel, dim3(32,8),  dim3(256), 0, stream, Pb, Hs, Hs, 257,2, 2,4);   // V3
    hipLaunchKernelGGL(k_sq, dim3(8,8), dim3(256), 0, stream, Pb, Pa);                   // Pa = A8
    hipLaunchKernelGGL(k_vlevel, dim3(16,8),  dim3(256), 0, stream, Pa, Hs, Hs, 2,4, 8,16);    // V4
    hipLaunchKernelGGL(k_sq, dim3(8,8), dim3(256), 0, stream, Pa, Pb);                   // Pb = A16

    // chain: h_{16(t+1)} = A16 h_{16t} + v4_t   (31 steps, 64 WGs)
    hipLaunchKernelGGL(k_zero_flags, dim3(8), dim3(256), 0, stream, flags);
    {
        int nstep = 31, mode = 1, nch = 1;
        void* args[] = { (void*)&Pb, (void*)&Hs, (void*)&Hs, (void*)&flags,
                         (void*)&nstep, (void*)&mode, (void*)&nch };
        if (hipLaunchCooperativeKernel((const void*)k_chain, dim3(64), dim3(256),
                                       args, 0, stream) != hipSuccess) {
            hipLaunchKernelGGL(k_chain, dim3(64), dim3(256), 0, stream,
                               Pb, Hs, Hs, flags, 31, 1, 1);
        }
    }

    // fill: h_{c*16+t+1} = A h_{c*16+t} + u   (15 steps, 32 chunks, 256 WGs x nch=8)
    hipLaunchKernelGGL(k_zero_flags, dim3(8), dim3(256), 0, stream, flags);
    {
        int nstep = 15, mode = 2, nch = 8;
        void* args[] = { (void*)&Wr, (void*)&Xh, (void*)&Hs, (void*)&flags,
                         (void*)&nstep, (void*)&mode, (void*)&nch };
        if (hipLaunchCooperativeKernel((const void*)k_chain, dim3(256), dim3(256),
                                       args, 0, stream) != hipSuccess) {
            hipLaunchKernelGGL(k_chain, dim3(256), dim3(256), 0, stream,
                               Wr, Xh, Hs, flags, 15, 2, 8);
        }
    }

    f16* Wro = Wr + (size_t)1024*1024;
    hipLaunchKernelGGL(k_gemm2, dim3(256, 8), dim3(256), 0, stream, Hs, Wro, Out);
}

// Round 13
// 1090.137 us; speedup vs baseline: 1.0370x; 1.0370x over previous
//
#include <hip/hip_runtime.h>
#include <hip/hip_bf16.h>

// RNNLayer: B=64, T=512, D_IN=D_H=D_OUT=1024.
// h_{t+1} = A h_t + u_t  (A = Wrh, u_t = x_t@Wxh^T + bh);  o_t = x_t@Wxo^T + h_t@Wro^T + bo
// Scan decomposition (sequential depth 511 -> 31 + 15):
//   tree:  v1=A u+u', v2=A2 v1+v1', v3=A4 v2+v2', v4=A8 v3+v3'  (plain GEMMs)
//   chain: h_{16(k+1)} = A16 h_{16k} + v4_k       (31 flag-sync steps, 64 WGs)
//   fill:  h_{16k+tau+1} = A h_{16k+tau} + u      (15 flag-sync steps, 256 WGs, nch=8)
// r12 -> r13: (1) gemm1 reverted to r11 BK=32 (BK=64's 128-B LDS rows were the
// Guideline-4 32-way bank conflict: SQ_LDS_BANK_CONFLICT 16.7M->50M). (2) k_chain
// publish: drop the redundant agent release fence — all h' stores are sc0sc1
// write-through and vmcnt(0)-drained per wave BEFORE __syncthreads, so data is at
// the coherence point before thread 0 stores the flag (sc0sc1). r12's chunk
// pipeline kept (verified, neutral).

typedef _Float16 f16;
typedef _Float16 f16x8 __attribute__((ext_vector_type(8)));
typedef _Float16 f16x4 __attribute__((ext_vector_type(4)));
typedef float f32x4 __attribute__((ext_vector_type(4)));
typedef int i32x4 __attribute__((ext_vector_type(4)));

#define T_LEN 512
#define BATCH 64
#define M_TOT (BATCH * T_LEN)   // 32768

// slab layout (per t): [bg 4][cblk 128][b 16][8] f16 = 65536 elems (128 KB)

// ---------- prep: stacked fp16 weights ----------
__global__ void k_prep_w(const float* __restrict__ Wh, const float* __restrict__ Wo,
                         f16* __restrict__ Wx, f16* __restrict__ Wr) {
    int n = blockIdx.x;              // 0..2047
    int t4 = threadIdx.x * 4;        // 0..1020
    const float* src = (n < 1024) ? (Wh + (size_t)n * 2048)
                                  : (Wo + (size_t)(n - 1024) * 2048);
    float4 a = *reinterpret_cast<const float4*>(src + t4);
    float4 b = *reinterpret_cast<const float4*>(src + 1024 + t4);
    f16x4 va, vb;
    va[0]=(f16)a.x; va[1]=(f16)a.y; va[2]=(f16)a.z; va[3]=(f16)a.w;
    vb[0]=(f16)b.x; vb[1]=(f16)b.y; vb[2]=(f16)b.z; vb[3]=(f16)b.w;
    *reinterpret_cast<f16x4*>(Wx + (size_t)n*1024 + t4) = va;
    *reinterpret_cast<f16x4*>(Wr + (size_t)n*1024 + t4) = vb;
}

// ---------- prep: X f32 -> Xf f16 row-major [32768][1024] ----------
__global__ void k_prep_x(const float* __restrict__ X, f16* __restrict__ Xf) {
    size_t i = ((size_t)blockIdx.x * 256 + threadIdx.x) * 8;   // grid 16384 x 256
    float4 a = *reinterpret_cast<const float4*>(X + i);
    float4 b = *reinterpret_cast<const float4*>(X + i + 4);
    f16x8 v;
    v[0]=(f16)a.x; v[1]=(f16)a.y; v[2]=(f16)a.z; v[3]=(f16)a.w;
    v[4]=(f16)b.x; v[5]=(f16)b.y; v[6]=(f16)b.z; v[7]=(f16)b.w;
    *reinterpret_cast<f16x8*>(Xf + i) = v;
}

// ---------- init: Hs[0] from H0 (packed layout) ----------
__global__ void k_init_h(const float* __restrict__ H0, f16* __restrict__ Hs) {
    int tid = blockIdx.x * 256 + threadIdx.x;   // 8192
    int b = tid >> 7, kb = tid & 127;
    float4 x0 = *reinterpret_cast<const float4*>(H0 + (size_t)b*1024 + kb*8);
    float4 x1 = *reinterpret_cast<const float4*>(H0 + (size_t)b*1024 + kb*8 + 4);
    f16x8 v;
    v[0]=(f16)x0.x; v[1]=(f16)x0.y; v[2]=(f16)x0.z; v[3]=(f16)x0.w;
    v[4]=(f16)x1.x; v[5]=(f16)x1.y; v[6]=(f16)x1.z; v[7]=(f16)x1.w;
    size_t idx = (size_t)(b >> 4)*16384 + (size_t)kb*128 + (size_t)(b & 15)*8;
    *reinterpret_cast<f16x8*>(Hs + idx) = v;
}

__global__ void k_zero_flags(unsigned int* __restrict__ flags) {
    flags[blockIdx.x * 256 + threadIdx.x] = 0;   // 2048 u32 (256 logical flags, 32B apart)
}

// ---------- phase 1: input projection GEMM (m97 structure, BK=32; verified r10/r11) ----------
__global__ __launch_bounds__(256) void k_gemm1(
    const f16* __restrict__ Af, const f16* __restrict__ Bm,
    const float* __restrict__ bh, const float* __restrict__ bo,
    f16* __restrict__ Xh, float* __restrict__ Out)
{
    __shared__ f16 As[128*32];   // 8 KB, linear row-major [128][32]
    __shared__ f16 Bs[128*32];   // 8 KB
    int m0 = blockIdx.x * 128;
    int n0 = blockIdx.y * 128;
    int t = threadIdx.x;
    int l = t & 63, w = t >> 6;
    int wm = w >> 1, wn = w & 1;
    int lm = l & 15, lh = l >> 4;

    f32x4 acc[4][4];
    #pragma unroll
    for (int i = 0; i < 4; i++)
        #pragma unroll
        for (int j = 0; j < 4; j++) acc[i][j] = (f32x4){0.f,0.f,0.f,0.f};

    const size_t lgo = (size_t)(l >> 2) * 2048 + (size_t)(l & 3) * 16;

    for (int kt = 0; kt < 32; ++kt) {
        __syncthreads();
        {
            const char* ga = (const char*)(Af + (size_t)(m0 + w*32) * 1024 + kt*32);
            const char* gb = (const char*)(Bm + (size_t)(n0 + w*32) * 1024 + kt*32);
            char* la = (char*)As + w * 2048;
            char* lb = (char*)Bs + w * 2048;
            #pragma unroll
            for (int j = 0; j < 2; ++j) {
                __builtin_amdgcn_global_load_lds(
                    (const __attribute__((address_space(1))) void*)(ga + (size_t)j*32768 + lgo),
                    (__attribute__((address_space(3))) void*)(la + j*1024), 16, 0, 0);
                __builtin_amdgcn_global_load_lds(
                    (const __attribute__((address_space(1))) void*)(gb + (size_t)j*32768 + lgo),
                    (__attribute__((address_space(3))) void*)(lb + j*1024), 16, 0, 0);
            }
        }
        asm volatile("s_waitcnt vmcnt(0)" ::: "memory");
        __syncthreads();

        f16x8 af[4], bf[4];
        #pragma unroll
        for (int i = 0; i < 4; i++)
            af[i] = *reinterpret_cast<const f16x8*>(As + (64*wm + 16*i + lm)*32 + 8*lh);
        #pragma unroll
        for (int j = 0; j < 4; j++)
            bf[j] = *reinterpret_cast<const f16x8*>(Bs + (64*wn + 16*j + lm)*32 + 8*lh);
        #pragma unroll
        for (int i = 0; i < 4; i++)
            #pragma unroll
            for (int j = 0; j < 4; j++)
                acc[i][j] = __builtin_amdgcn_mfma_f32_16x16x32_f16(af[i], bf[j], acc[i][j], 0, 0, 0);
    }

    int r0 = lh * 4;
    bool isH = (n0 < 1024);
    #pragma unroll
    for (int i = 0; i < 4; i++)
        #pragma unroll
        for (int j = 0; j < 4; j++) {
            int gmb = m0 + 64*wm + 16*i + r0;
            int gn  = n0 + 64*wn + 16*j + lm;
            #pragma unroll
            for (int r = 0; r < 4; r++) {
                float v = acc[i][j][r];
                int gm = gmb + r;                 // m = b*512 + t
                if (isH) {
                    int tt = gm & 511, bb = gm >> 9;
                    size_t idx = (size_t)tt*65536 + (size_t)(bb>>4)*16384
                               + (size_t)(gn>>3)*128 + (size_t)(bb&15)*8 + (gn&7);
                    Xh[idx] = (f16)(v + bh[gn]);
                } else {
                    Out[(size_t)gm*1024 + (gn - 1024)] = v + bo[gn - 1024];
                }
            }
        }
}

// ---------- matrix squaring: Pout = P*P (B transposed in-LDS; verified r9) ----------
__global__ __launch_bounds__(256) void k_sq(const f16* __restrict__ P, f16* __restrict__ Pout)
{
    __shared__ f16 As[128][40];
    __shared__ f16 Bs[128][40];
    int m0 = blockIdx.x * 128, n0 = blockIdx.y * 128;
    int t = threadIdx.x;
    int l = t & 63, wid = t >> 6;
    int wm = wid >> 1, wn = wid & 1;
    int lm = l & 15, lh = l >> 4;

    f32x4 acc[4][4];
    #pragma unroll
    for (int i = 0; i < 4; i++)
        #pragma unroll
        for (int j = 0; j < 4; j++) acc[i][j] = (f32x4){0.f,0.f,0.f,0.f};

    for (int kt = 0; kt < 32; ++kt) {
        __syncthreads();
        #pragma unroll
        for (int c = t; c < 512; c += 256) {       // A rows m, k-contig
            int row = c >> 2, q = c & 3;
            *reinterpret_cast<float4*>(&As[row][q*8]) =
                *reinterpret_cast<const float4*>(P + (size_t)(m0+row)*1024 + kt*32 + q*8);
        }
        #pragma unroll
        for (int c = t; c < 512; c += 256) {       // Bs[n][k] = P[k][n0+n]
            int r = c >> 4, q = c & 15;
            f16x8 v = *reinterpret_cast<const f16x8*>(P + (size_t)(kt*32 + r)*1024 + n0 + q*8);
            #pragma unroll
            for (int e = 0; e < 8; ++e) Bs[q*8+e][r] = v[e];
        }
        __syncthreads();

        f16x8 af[4], bf[4];
        #pragma unroll
        for (int i = 0; i < 4; i++)
            af[i] = *reinterpret_cast<const f16x8*>(&As[64*wm + 16*i + lm][8*lh]);
        #pragma unroll
        for (int j = 0; j < 4; j++)
            bf[j] = *reinterpret_cast<const f16x8*>(&Bs[64*wn + 16*j + lm][8*lh]);
        #pragma unroll
        for (int i = 0; i < 4; i++)
            #pragma unroll
            for (int j = 0; j < 4; j++)
                acc[i][j] = __builtin_amdgcn_mfma_f32_16x16x32_f16(af[i], bf[j], acc[i][j], 0, 0, 0);
    }

    int r0 = lh * 4;
    #pragma unroll
    for (int i = 0; i < 4; i++)
        #pragma unroll
        for (int j = 0; j < 4; j++) {
            int gmb = m0 + 64*wm + 16*i + r0;
            int gn  = n0 + 64*wn + 16*j + lm;
            #pragma unroll
            for (int r = 0; r < 4; r++)
                Pout[(size_t)(gmb+r)*1024 + gn] = (f16)acc[i][j][r];
        }
}

// ---------- v-level GEMM: Dst[k] = M * Src[f(2k)] + Src[f(2k+1)] (verified r11) ----------
__global__ __launch_bounds__(256) void k_vlevel(
    const f16* __restrict__ M, const f16* __restrict__ Src, f16* __restrict__ Dst,
    int srcOff, int srcStep, int dstOff, int dstStep)
{
    __shared__ f16 As[4096];   // 8 KB
    __shared__ f16 Bs[128*32]; // 8 KB, [row][32] linear
    int m0 = blockIdx.x * 128;          // rows m = k*64 + b
    int n0 = blockIdx.y * 128;
    int t = threadIdx.x;
    int l = t & 63, w = t >> 6;
    int wm = w >> 1, wn = w & 1;
    int lm = l & 15, lh = l >> 4;

    f32x4 acc[4][4];
    #pragma unroll
    for (int i = 0; i < 4; i++)
        #pragma unroll
        for (int j = 0; j < 4; j++) acc[i][j] = (f32x4){0.f,0.f,0.f,0.f};

    const size_t lgo = (size_t)(l >> 2) * 2048 + (size_t)(l & 3) * 16;   // B (2048 B/row)
    const int kd0 = m0 >> 6;

    for (int kt = 0; kt < 32; ++kt) {
        __syncthreads();
        {
            #pragma unroll
            for (int j = 0; j < 2; ++j) {
                int ch  = w*2 + j;               // 0..7
                int kdl = ch >> 2, bgc = ch & 3;
                size_t slab = (size_t)(srcOff + srcStep * (2*(kd0 + kdl)));
                const char* gsrc = (const char*)(Src + slab*65536
                                    + (size_t)bgc*16384 + (size_t)kt*512) + (size_t)l*16;
                __builtin_amdgcn_global_load_lds(
                    (const __attribute__((address_space(1))) void*)gsrc,
                    (__attribute__((address_space(3))) void*)((char*)As + ch*1024), 16, 0, 0);
            }
            const char* gb = (const char*)(M + (size_t)(n0 + w*32) * 1024 + kt*32);
            char* lb = (char*)Bs + w * 2048;
            #pragma unroll
            for (int j = 0; j < 2; ++j)
                __builtin_amdgcn_global_load_lds(
                    (const __attribute__((address_space(1))) void*)(gb + (size_t)j*32768 + lgo),
                    (__attribute__((address_space(3))) void*)(lb + j*1024), 16, 0, 0);
        }
        asm volatile("s_waitcnt vmcnt(0)" ::: "memory");
        __syncthreads();

        f16x8 af[4], bf[4];
        #pragma unroll
        for (int i = 0; i < 4; i++)
            af[i] = *reinterpret_cast<const f16x8*>(As + wm*2048 + i*512 + lh*128 + lm*8);
        #pragma unroll
        for (int j = 0; j < 4; j++)
            bf[j] = *reinterpret_cast<const f16x8*>(Bs + (64*wn + 16*j + lm)*32 + 8*lh);
        #pragma unroll
        for (int i = 0; i < 4; i++)
            #pragma unroll
            for (int j = 0; j < 4; j++)
                acc[i][j] = __builtin_amdgcn_mfma_f32_16x16x32_f16(af[i], bf[j], acc[i][j], 0, 0, 0);
    }

    int r0 = lh * 4;
    #pragma unroll
    for (int i = 0; i < 4; i++)
        #pragma unroll
        for (int j = 0; j < 4; j++) {
            int gmb = m0 + 64*wm + 16*i + r0;
            int gn  = n0 + 64*wn + 16*j + lm;
            #pragma unroll
            for (int r = 0; r < 4; r++) {
                int gm = gmb + r;
                int kd = gm >> 6, bb = gm & 63;
                size_t pidx = (size_t)(bb>>4)*16384 + (size_t)(gn>>3)*128
                            + (size_t)(bb&15)*8 + (gn&7);
                size_t aslab = (size_t)(srcOff + srcStep * (2*kd + 1));
                float add = (float)Src[aslab*65536 + pidx];
                size_t dslab = (size_t)(dstOff + dstStep * kd);
                Dst[dslab*65536 + pidx] = (f16)(acc[i][j][r] + add);
            }
        }
}

// ---------- flag-sync recurrence kernel (r12 pipeline; r13: fence-free publish) ----------
// mode 1 (CHAIN): 64 WGs, nch=1. step t: Hs[16t] -> Hs[16t+16], u = Hs[16t+8] (v4).
//   decode: r=wg&7, s=wg>>3: g=bg=r>>1, cg=((r&1)<<3)|s, p=0  (group on XCD pair)
// mode 2 (FILL): 256 WGs, nch=8. step t: Hs[c*16+t] -> +1, u = Xh[c*16+t], c=p*8+i.
//   decode: r=wg&7, s=wg>>3: g=2r+(s>>4), cg=s&15, p=g>>2, bg=g&3 (group on one XCD)
// Publish correctness without fence: every h' store is sc0sc1 (write-through to
// coherence point) and each wave drains its own stores with vmcnt(0) BEFORE
// __syncthreads; thread 0's sc0sc1 flag store therefore cannot pass the data.
__global__ void __launch_bounds__(256) __attribute__((amdgpu_waves_per_eu(1, 1)))
k_chain(
    const f16* __restrict__ W,        // [1024][1024] row-major (A or A16)
    const f16* __restrict__ U,        // u base (slab-packed)
    f16* __restrict__ Hs,
    unsigned int* __restrict__ flags,
    int nstep, int mode, int nch)
{
    int wg = blockIdx.x;
    int r_ = wg & 7, s_ = wg >> 3;
    int g, cg, p, bg;
    if (mode == 1) { g = r_ >> 1; cg = ((r_ & 1) << 3) | s_; p = 0;       bg = g;     }
    else           { g = 2*r_ + (s_ >> 4); cg = s_ & 15;     p = g >> 2;  bg = g & 3; }
    int w  = threadIdx.x >> 6;
    int l  = threadIdx.x & 63;
    int lm = l & 15, lh = l >> 4;
    int ccol = cg * 64 + w * 16 + lm;

    __shared__ f16 hbuf[2][16384];      // 64 KB double-buffered h slab
    __shared__ float lt[4][16][17];

    // register-resident recurrent weights: 16 cols x K=1024 = 128 VGPRs/lane.
    f16x8 bw[32];
    #pragma unroll
    for (int kt = 0; kt < 32; ++kt)
        bw[kt] = *reinterpret_cast<const f16x8*>(W + (size_t)ccol * 1024 + kt*32 + lh*8);
    #pragma unroll
    for (int kt = 0; kt < 32; ++kt)
        asm volatile("" : "+v"(bw[kt]));

    const int flagBase = g * 16;
    int b_ep = l & 15, cb_ep = l >> 4;
    int cblk = cg*8 + w*2 + cb_ep;

    for (int t = 0; t < nstep; ++t) {
        if (t > 0) {
            if (threadIdx.x < 16) {
                unsigned int tgt = (unsigned int)t;
                const unsigned int* fp = &flags[(flagBase + (int)threadIdx.x) * 8];
                while (__hip_atomic_load(fp, __ATOMIC_RELAXED, __HIP_MEMORY_SCOPE_AGENT) < tgt)
                    __builtin_amdgcn_s_sleep(1);
            }
            __syncthreads();
            asm volatile("" ::: "memory");
        }

        // slab indices for chunk i
        auto slabs = [&](int i, size_t& rS, size_t& wS, size_t& uS) {
            if (mode == 1) { rS = (size_t)(16*t); wS = rS + 16; uS = rS + 8; }
            else { int c = p*nch + i; rS = (size_t)(c*16 + t); wS = rS + 1; uS = rS; }
        };
        auto STAGE = [&](size_t rS, int buf) {
            const char* gsrc = (const char*)Hs + (rS*65536 + (size_t)bg*16384)*2
                             + (size_t)w*8192 + (size_t)l*16;
            char* ldst = (char*)&hbuf[buf][0] + (size_t)w*8192;
            #pragma unroll
            for (int q = 0; q < 8; ++q)
                __builtin_amdgcn_global_load_lds(
                    (const __attribute__((address_space(1))) void*)(gsrc + q*1024),
                    (__attribute__((address_space(3))) void*)(ldst + q*1024),
                    16, 0, 0);
        };
        auto XV = [&](size_t uS) -> f16x8 {
            f16x8 v = {};
            if (l < 32)
                v = *reinterpret_cast<const f16x8*>(
                    U + uS*65536 + (size_t)bg*16384 + (size_t)cblk*128 + b_ep*8);
            return v;
        };

        // prologue: chunk 0 -> buf 0 (9 memops/wave)
        f16x8 xv0, xv1;
        {
            size_t rS, wS, uS; slabs(0, rS, wS, uS);
            STAGE(rS, 0);
            xv0 = XV(uS);
        }

        for (int i = 0; i < nch; ++i) {
            int nxt = i + 1;
            if (nxt < nch) {
                size_t rS, wS, uS; slabs(nxt, rS, wS, uS);
                STAGE(rS, nxt & 1);
                if (nxt & 1) xv1 = XV(uS); else xv0 = XV(uS);
                asm volatile("s_waitcnt vmcnt(9)" ::: "memory");
            } else {
                asm volatile("s_waitcnt vmcnt(0)" ::: "memory");
            }
            __syncthreads();

            const f16* cbuf = &hbuf[i & 1][0];
            f32x4 a0 = (f32x4){0.f,0.f,0.f,0.f};
            f32x4 a1 = (f32x4){0.f,0.f,0.f,0.f};
            #pragma unroll
            for (int kt = 0; kt < 32; ++kt) {
                f16x8 af = *reinterpret_cast<const f16x8*>(&cbuf[(size_t)(kt*4 + lh)*128 + lm*8]);
                if (kt & 1) a1 = __builtin_amdgcn_mfma_f32_16x16x32_f16(af, bw[kt], a1, 0, 0, 0);
                else        a0 = __builtin_amdgcn_mfma_f32_16x16x32_f16(af, bw[kt], a0, 0, 0, 0);
            }
            f32x4 acc = a0 + a1;

            #pragma unroll
            for (int r = 0; r < 4; ++r)
                lt[w][lh*4 + r][lm] = acc[r];
            // wave-private RAW through LDS (compiler inserts lgkmcnt)

            if (l < 32) {
                f16x8 xvc = (i & 1) ? xv1 : xv0;
                size_t rS, wS, uS; slabs(i, rS, wS, uS);
                f16x8 hv;
                #pragma unroll
                for (int e = 0; e < 8; ++e)
                    hv[e] = (f16)(lt[w][b_ep][cb_ep*8 + e] + (float)xvc[e]);
                f16* dst = Hs + wS*65536 + (size_t)bg*16384 + (size_t)cblk*128 + b_ep*8;
                i32x4 iv = __builtin_bit_cast(i32x4, hv);
                asm volatile("global_store_dwordx4 %0, %1, off sc0 sc1"
                             :: "v"(dst), "v"(iv) : "memory");
            }
            __syncthreads();   // all waves done reading buf[i&1] before it is restaged
        }

        asm volatile("s_waitcnt vmcnt(0)" ::: "memory");
        __syncthreads();
        if (threadIdx.x == 0) {
            unsigned int* fp = &flags[(flagBase + cg)*8];
            unsigned int val = (unsigned int)(t + 1);
            asm volatile("global_store_dword %0, %1, off sc0 sc1"
                         :: "v"(fp), "v"(val) : "memory");
        }
    }
}

// ---------- phase 3: output GEMM  Out += Hs @ Wro^T (verified r11) ----------
__global__ __launch_bounds__(256) void k_gemm2(
    const f16* __restrict__ Hs, const f16* __restrict__ Bm, float* __restrict__ Out)
{
    __shared__ f16 As[4096];   // 8 KB: [ttloc2][bg4][kblk4][b16][e8]
    __shared__ f16 Bs[128*32]; // 8 KB
    int m0 = blockIdx.x * 128;          // m' = t*64 + b
    int n0 = blockIdx.y * 128;
    int t = threadIdx.x;
    int l = t & 63, w = t >> 6;
    int wm = w >> 1, wn = w & 1;
    int lm = l & 15, lh = l >> 4;

    f32x4 acc[4][4];
    #pragma unroll
    for (int i = 0; i < 4; i++)
        #pragma unroll
        for (int j = 0; j < 4; j++) acc[i][j] = (f32x4){0.f,0.f,0.f,0.f};

    const size_t lgo = (size_t)(l >> 2) * 2048 + (size_t)(l & 3) * 16;
    const int tt0 = m0 >> 6;

    for (int kt = 0; kt < 32; ++kt) {
        __syncthreads();
        {
            #pragma unroll
            for (int j = 0; j < 2; ++j) {
                int ch  = w*2 + j;               // 0..7
                int ttl = ch >> 2, bgc = ch & 3;
                const char* gsrc = (const char*)(Hs + (size_t)(tt0 + ttl)*65536
                                    + (size_t)bgc*16384 + (size_t)kt*512) + (size_t)l*16;
                __builtin_amdgcn_global_load_lds(
                    (const __attribute__((address_space(1))) void*)gsrc,
                    (__attribute__((address_space(3))) void*)((char*)As + ch*1024), 16, 0, 0);
            }
            const char* gb = (const char*)(Bm + (size_t)(n0 + w*32) * 1024 + kt*32);
            char* lb = (char*)Bs + w * 2048;
            #pragma unroll
            for (int j = 0; j < 2; ++j)
                __builtin_amdgcn_global_load_lds(
                    (const __attribute__((address_space(1))) void*)(gb + (size_t)j*32768 + lgo),
                    (__attribute__((address_space(3))) void*)(lb + j*1024), 16, 0, 0);
        }
        asm volatile("s_waitcnt vmcnt(0)" ::: "memory");
        __syncthreads();

        f16x8 af[4], bf[4];
        #pragma unroll
        for (int i = 0; i < 4; i++)
            af[i] = *reinterpret_cast<const f16x8*>(As + wm*2048 + i*512 + lh*128 + lm*8);
        #pragma unroll
        for (int j = 0; j < 4; j++)
            bf[j] = *reinterpret_cast<const f16x8*>(Bs + (64*wn + 16*j + lm)*32 + 8*lh);
        #pragma unroll
        for (int i = 0; i < 4; i++)
            #pragma unroll
            for (int j = 0; j < 4; j++)
                acc[i][j] = __builtin_amdgcn_mfma_f32_16x16x32_f16(af[i], bf[j], acc[i][j], 0, 0, 0);
    }

    int r0 = lh * 4;
    #pragma unroll
    for (int i = 0; i < 4; i++)
        #pragma unroll
        for (int j = 0; j < 4; j++) {
            int gmb = m0 + 64*wm + 16*i + r0;
            int gn  = n0 + 64*wn + 16*j + lm;
            #pragma unroll
            for (int r = 0; r < 4; r++) {
                int gm = gmb + r;               // m' = t*64 + b
                int bb = gm & 63, tt = gm >> 6;
                size_t o = ((size_t)bb*512 + tt)*1024 + gn;
                Out[o] += acc[i][j][r];
            }
        }
}

// ---------- workspace layout (bytes) — 136.07 MB total ----------
// [0, 4M)      Wx (gemm1); afterwards Pa @0, Pb @2M (A-power ping-pong)
// [4M, 8M)     Wr  (rows 0..1023 = A = Wrh, rows 1024..2047 = Wro)
// [8M, 72M)    Xh  [512 slabs]
// [72M, 136M)  Hs  [512 slabs]; ALSO Xf f16 [32768][1024] pre-gemm1 (dead after);
//              then V1 -> slabs 1..256, V2 -> odd 257.., V3 -> 2+4m, V4 -> 16c+8
// [136M, +8K)  flags u32[2048] (256 logical flags, 32B stride)

extern "C" void kernel_launch(void* const* d_in, const int* in_sizes, int n_in,
                              void* d_out, int out_size, void* d_ws, size_t ws_size,
                              hipStream_t stream) {
    const float* X  = (const float*)d_in[0];
    const float* H0 = (const float*)d_in[1];
    const float* Wh = (const float*)d_in[2];
    const float* bh = (const float*)d_in[3];
    const float* Wo = (const float*)d_in[4];
    const float* bo = (const float*)d_in[5];
    float* Out = (float*)d_out;

    char* ws = (char*)d_ws;
    f16* Wx = (f16*)(ws);
    f16* Pa = (f16*)(ws);                               // aliases Wx (dead after gemm1)
    f16* Pb = (f16*)(ws + (size_t)2*1024*1024);
    f16* Wr = (f16*)(ws + (size_t)4*1024*1024);
    f16* Xh = (f16*)(ws + (size_t)8*1024*1024);
    f16* Hs = (f16*)(ws + (size_t)8*1024*1024 + (size_t)M_TOT*1024*2);
    f16* Xf = Hs;                                       // aliases Hs (dead until after gemm1)
    unsigned int* flags = (unsigned int*)(ws + (size_t)8*1024*1024 + (size_t)2*M_TOT*1024*2);

    hipLaunchKernelGGL(k_prep_w, dim3(2048), dim3(256), 0, stream, Wh, Wo, Wx, Wr);
    hipLaunchKernelGGL(k_prep_x, dim3(16384), dim3(256), 0, stream, X, Xf);
    hipLaunchKernelGGL(k_gemm1, dim3(256, 16), dim3(256), 0, stream, Xf, Wx, bh, bo, Xh, Out);
    hipLaunchKernelGGL(k_init_h, dim3(32), dim3(256), 0, stream, H0, Hs);   // after gemm1: Xf dead

    // A-power / v-level interleave (each value consumed before overwrite)
    hipLaunchKernelGGL(k_sq, dim3(8,8), dim3(256), 0, stream, Wr, Pa);                   // Pa = A2
    hipLaunchKernelGGL(k_vlevel, dim3(128,8), dim3(256), 0, stream, Wr, Xh, Hs, 0,1, 1,1);     // V1
    hipLaunchKernelGGL(k_vlevel, dim3(64,8),  dim3(256), 0, stream, Pa, Hs, Hs, 1,1, 257,2);   // V2
    hipLaunchKernelGGL(k_sq, dim3(8,8), dim3(256), 0, stream, Pa, Pb);                   // Pb = A4
    hipLaunchKernelGGL(k_vlevel, dim3(32,8),  dim3(256), 0, stream, Pb, Hs, Hs, 257,2, 2,4);   // V3
    hipLaunchKernelGGL(k_sq, dim3(8,8), dim3(256), 0, stream, Pb, Pa);                   // Pa = A8
    hipLaunchKernelGGL(k_vlevel, dim3(16,8),  dim3(256), 0, stream, Pa, Hs, Hs, 2,4, 8,16);    // V4
    hipLaunchKernelGGL(k_sq, dim3(8,8), dim3(256), 0, stream, Pa, Pb);                   // Pb = A16

    // chain: h_{16(t+1)} = A16 h_{16t} + v4_t   (31 steps, 64 WGs)
    hipLaunchKernelGGL(k_zero_flags, dim3(8), dim3(256), 0, stream, flags);
    {
        int nstep = 31, mode = 1, nch = 1;
        void* args[] = { (void*)&Pb, (void*)&Hs, (void*)&Hs, (void*)&flags,
                         (void*)&nstep, (void*)&mode, (void*)&nch };
        if (hipLaunchCooperativeKernel((const void*)k_chain, dim3(64), dim3(256),
                                       args, 0, stream) != hipSuccess) {
            hipLaunchKernelGGL(k_chain, dim3(64), dim3(256), 0, stream,
                               Pb, Hs, Hs, flags, 31, 1, 1);
        }
    }

    // fill: h_{c*16+t+1} = A h_{c*16+t} + u   (15 steps, 32 chunks, 256 WGs x nch=8)
    hipLaunchKernelGGL(k_zero_flags, dim3(8), dim3(256), 0, stream, flags);
    {
        int nstep = 15, mode = 2, nch = 8;
        void* args[] = { (void*)&Wr, (void*)&Xh, (void*)&Hs, (void*)&flags,
                         (void*)&nstep, (void*)&mode, (void*)&nch };
        if (hipLaunchCooperativeKernel((const void*)k_chain, dim3(256), dim3(256),
                                       args, 0, stream) != hipSuccess) {
            hipLaunchKernelGGL(k_chain, dim3(256), dim3(256), 0, stream,
                               Wr, Xh, Hs, flags, 15, 2, 8);
        }
    }

    f16* Wro = Wr + (size_t)1024*1024;
    hipLaunchKernelGGL(k_gemm2, dim3(256, 8), dim3(256), 0, stream, Hs, Wro, Out);
}

// Round 14
// 1015.892 us; speedup vs baseline: 1.1128x; 1.0731x over previous
//
#include <hip/hip_runtime.h>
#include <hip/hip_bf16.h>

// RNNLayer: B=64, T=512, D_IN=D_H=D_OUT=1024.
// h_{t+1} = A h_t + u_t  (A = Wrh, u_t = x_t@Wxh^T + bh);  o_t = x_t@Wxo^T + h_t@Wro^T + bo
// Scan decomposition (sequential depth 511 -> 31 + 15):
//   tree:  v1=A u+u', v2=A2 v1+v1', v3=A4 v2+v2', v4=A8 v3+v3'  (4 fused GEMM dispatches)
//   chain: h_{16(k+1)} = A16 h_{16k} + v4_k       (31 flag-sync steps, 64 WGs)
//   fill:  h_{16k+tau+1} = A h_{16k+tau} + u      (15 flag-sync steps, 256 WGs, nch=8)
// r13 -> r14: (1) each A-power squaring fused into its paired v-level dispatch
// (k_tree: blockIdx.x < nx -> vlevel body, else -> sq body; writes disjoint,
// audited) — removes 4 serial latency-bound 64-WG dispatches. (2) launch count
// 17 -> 10: prep_w+prep_x fused, init_h+zero_flags fused, mid-stream zero_flags
// replaced by a disjoint fill flag bank (flags+512, zeroed upfront).

typedef _Float16 f16;
typedef _Float16 f16x8 __attribute__((ext_vector_type(8)));
typedef _Float16 f16x4 __attribute__((ext_vector_type(4)));
typedef float f32x4 __attribute__((ext_vector_type(4)));
typedef int i32x4 __attribute__((ext_vector_type(4)));

#define T_LEN 512
#define BATCH 64
#define M_TOT (BATCH * T_LEN)   // 32768

// slab layout (per t): [bg 4][cblk 128][b 16][8] f16 = 65536 elems (128 KB)

// ---------- prep: stacked fp16 weights + X f32->f16 (fused) ----------
__global__ void k_prep(const float* __restrict__ Wh, const float* __restrict__ Wo,
                       const float* __restrict__ X,
                       f16* __restrict__ Wx, f16* __restrict__ Wr, f16* __restrict__ Xf) {
    int bid = blockIdx.x;
    if (bid < 16384) {
        size_t i = ((size_t)bid * 256 + threadIdx.x) * 8;
        float4 a = *reinterpret_cast<const float4*>(X + i);
        float4 b = *reinterpret_cast<const float4*>(X + i + 4);
        f16x8 v;
        v[0]=(f16)a.x; v[1]=(f16)a.y; v[2]=(f16)a.z; v[3]=(f16)a.w;
        v[4]=(f16)b.x; v[5]=(f16)b.y; v[6]=(f16)b.z; v[7]=(f16)b.w;
        *reinterpret_cast<f16x8*>(Xf + i) = v;
    } else {
        int n = bid - 16384;             // 0..2047
        int t4 = threadIdx.x * 4;        // 0..1020
        const float* src = (n < 1024) ? (Wh + (size_t)n * 2048)
                                      : (Wo + (size_t)(n - 1024) * 2048);
        float4 a = *reinterpret_cast<const float4*>(src + t4);
        float4 b = *reinterpret_cast<const float4*>(src + 1024 + t4);
        f16x4 va, vb;
        va[0]=(f16)a.x; va[1]=(f16)a.y; va[2]=(f16)a.z; va[3]=(f16)a.w;
        vb[0]=(f16)b.x; vb[1]=(f16)b.y; vb[2]=(f16)b.z; vb[3]=(f16)b.w;
        *reinterpret_cast<f16x4*>(Wx + (size_t)n*1024 + t4) = va;
        *reinterpret_cast<f16x4*>(Wr + (size_t)n*1024 + t4) = vb;
    }
}

// ---------- init: Hs[0] from H0 (packed) + zero both flag banks (fused) ----------
__global__ void k_init(const float* __restrict__ H0, f16* __restrict__ Hs,
                       unsigned int* __restrict__ flags) {
    int bid = blockIdx.x;
    if (bid < 32) {
        int tid = bid * 256 + threadIdx.x;   // 8192
        int b = tid >> 7, kb = tid & 127;
        float4 x0 = *reinterpret_cast<const float4*>(H0 + (size_t)b*1024 + kb*8);
        float4 x1 = *reinterpret_cast<const float4*>(H0 + (size_t)b*1024 + kb*8 + 4);
        f16x8 v;
        v[0]=(f16)x0.x; v[1]=(f16)x0.y; v[2]=(f16)x0.z; v[3]=(f16)x0.w;
        v[4]=(f16)x1.x; v[5]=(f16)x1.y; v[6]=(f16)x1.z; v[7]=(f16)x1.w;
        size_t idx = (size_t)(b >> 4)*16384 + (size_t)kb*128 + (size_t)(b & 15)*8;
        *reinterpret_cast<f16x8*>(Hs + idx) = v;
    } else {
        flags[(bid - 32) * 256 + threadIdx.x] = 0;   // 16 blocks -> 4096 u32 (16 KB)
    }
}

// ---------- phase 1: input projection GEMM (m97 structure, BK=32; verified r10-r13) ----------
__global__ __launch_bounds__(256) void k_gemm1(
    const f16* __restrict__ Af, const f16* __restrict__ Bm,
    const float* __restrict__ bh, const float* __restrict__ bo,
    f16* __restrict__ Xh, float* __restrict__ Out)
{
    __shared__ f16 As[128*32];   // 8 KB, linear row-major [128][32]
    __shared__ f16 Bs[128*32];   // 8 KB
    int m0 = blockIdx.x * 128;
    int n0 = blockIdx.y * 128;
    int t = threadIdx.x;
    int l = t & 63, w = t >> 6;
    int wm = w >> 1, wn = w & 1;
    int lm = l & 15, lh = l >> 4;

    f32x4 acc[4][4];
    #pragma unroll
    for (int i = 0; i < 4; i++)
        #pragma unroll
        for (int j = 0; j < 4; j++) acc[i][j] = (f32x4){0.f,0.f,0.f,0.f};

    const size_t lgo = (size_t)(l >> 2) * 2048 + (size_t)(l & 3) * 16;

    for (int kt = 0; kt < 32; ++kt) {
        __syncthreads();
        {
            const char* ga = (const char*)(Af + (size_t)(m0 + w*32) * 1024 + kt*32);
            const char* gb = (const char*)(Bm + (size_t)(n0 + w*32) * 1024 + kt*32);
            char* la = (char*)As + w * 2048;
            char* lb = (char*)Bs + w * 2048;
            #pragma unroll
            for (int j = 0; j < 2; ++j) {
                __builtin_amdgcn_global_load_lds(
                    (const __attribute__((address_space(1))) void*)(ga + (size_t)j*32768 + lgo),
                    (__attribute__((address_space(3))) void*)(la + j*1024), 16, 0, 0);
                __builtin_amdgcn_global_load_lds(
                    (const __attribute__((address_space(1))) void*)(gb + (size_t)j*32768 + lgo),
                    (__attribute__((address_space(3))) void*)(lb + j*1024), 16, 0, 0);
            }
        }
        asm volatile("s_waitcnt vmcnt(0)" ::: "memory");
        __syncthreads();

        f16x8 af[4], bf[4];
        #pragma unroll
        for (int i = 0; i < 4; i++)
            af[i] = *reinterpret_cast<const f16x8*>(As + (64*wm + 16*i + lm)*32 + 8*lh);
        #pragma unroll
        for (int j = 0; j < 4; j++)
            bf[j] = *reinterpret_cast<const f16x8*>(Bs + (64*wn + 16*j + lm)*32 + 8*lh);
        #pragma unroll
        for (int i = 0; i < 4; i++)
            #pragma unroll
            for (int j = 0; j < 4; j++)
                acc[i][j] = __builtin_amdgcn_mfma_f32_16x16x32_f16(af[i], bf[j], acc[i][j], 0, 0, 0);
    }

    int r0 = lh * 4;
    bool isH = (n0 < 1024);
    #pragma unroll
    for (int i = 0; i < 4; i++)
        #pragma unroll
        for (int j = 0; j < 4; j++) {
            int gmb = m0 + 64*wm + 16*i + r0;
            int gn  = n0 + 64*wn + 16*j + lm;
            #pragma unroll
            for (int r = 0; r < 4; r++) {
                float v = acc[i][j][r];
                int gm = gmb + r;                 // m = b*512 + t
                if (isH) {
                    int tt = gm & 511, bb = gm >> 9;
                    size_t idx = (size_t)tt*65536 + (size_t)(bb>>4)*16384
                               + (size_t)(gn>>3)*128 + (size_t)(bb&15)*8 + (gn&7);
                    Xh[idx] = (f16)(v + bh[gn]);
                } else {
                    Out[(size_t)gm*1024 + (gn - 1024)] = v + bo[gn - 1024];
                }
            }
        }
}

// ---------- fused tree dispatch: vlevel (blockIdx.x < nx) + matrix squaring ----------
// vlevel: Dst[k] = M * Src[srcOff+srcStep*2k] + Src[srcOff+srcStep*(2k+1)]  (r11-verified)
// sq:     Pout = P*P (B transposed in-LDS; r9-verified), m0 = (blockIdx.x-nx)*128
// All writes within one dispatch are disjoint (audited r14).
__global__ __launch_bounds__(256) void k_tree(
    const f16* __restrict__ M, const f16* __restrict__ Src, f16* __restrict__ Dst,
    int srcOff, int srcStep, int dstOff, int dstStep, int nx,
    const f16* __restrict__ P, f16* __restrict__ Pout)
{
    __shared__ __align__(16) char pool[20480];
    int t = threadIdx.x;
    int l = t & 63, w = t >> 6;
    int wm = w >> 1, wn = w & 1;
    int lm = l & 15, lh = l >> 4;
    int n0 = blockIdx.y * 128;

    f32x4 acc[4][4];
    #pragma unroll
    for (int i = 0; i < 4; i++)
        #pragma unroll
        for (int j = 0; j < 4; j++) acc[i][j] = (f32x4){0.f,0.f,0.f,0.f};

    if (blockIdx.x < nx) {
        // ---------------- vlevel body ----------------
        f16* As = (f16*)pool;            // 8 KB: [kdl2][bg4][kblk4][b16][e8]
        f16* Bs = (f16*)(pool + 8192);   // 8 KB: [row][32] linear
        int m0 = blockIdx.x * 128;
        const size_t lgo = (size_t)(l >> 2) * 2048 + (size_t)(l & 3) * 16;
        const int kd0 = m0 >> 6;

        for (int kt = 0; kt < 32; ++kt) {
            __syncthreads();
            {
                #pragma unroll
                for (int j = 0; j < 2; ++j) {
                    int ch  = w*2 + j;               // 0..7
                    int kdl = ch >> 2, bgc = ch & 3;
                    size_t slab = (size_t)(srcOff + srcStep * (2*(kd0 + kdl)));
                    const char* gsrc = (const char*)(Src + slab*65536
                                        + (size_t)bgc*16384 + (size_t)kt*512) + (size_t)l*16;
                    __builtin_amdgcn_global_load_lds(
                        (const __attribute__((address_space(1))) void*)gsrc,
                        (__attribute__((address_space(3))) void*)((char*)As + ch*1024), 16, 0, 0);
                }
                const char* gb = (const char*)(M + (size_t)(n0 + w*32) * 1024 + kt*32);
                char* lb = (char*)Bs + w * 2048;
                #pragma unroll
                for (int j = 0; j < 2; ++j)
                    __builtin_amdgcn_global_load_lds(
                        (const __attribute__((address_space(1))) void*)(gb + (size_t)j*32768 + lgo),
                        (__attribute__((address_space(3))) void*)(lb + j*1024), 16, 0, 0);
            }
            asm volatile("s_waitcnt vmcnt(0)" ::: "memory");
            __syncthreads();

            f16x8 af[4], bf[4];
            #pragma unroll
            for (int i = 0; i < 4; i++)
                af[i] = *reinterpret_cast<const f16x8*>(As + wm*2048 + i*512 + lh*128 + lm*8);
            #pragma unroll
            for (int j = 0; j < 4; j++)
                bf[j] = *reinterpret_cast<const f16x8*>(Bs + (64*wn + 16*j + lm)*32 + 8*lh);
            #pragma unroll
            for (int i = 0; i < 4; i++)
                #pragma unroll
                for (int j = 0; j < 4; j++)
                    acc[i][j] = __builtin_amdgcn_mfma_f32_16x16x32_f16(af[i], bf[j], acc[i][j], 0, 0, 0);
        }

        int r0 = lh * 4;
        #pragma unroll
        for (int i = 0; i < 4; i++)
            #pragma unroll
            for (int j = 0; j < 4; j++) {
                int gmb = m0 + 64*wm + 16*i + r0;
                int gn  = n0 + 64*wn + 16*j + lm;
                #pragma unroll
                for (int r = 0; r < 4; r++) {
                    int gm = gmb + r;
                    int kd = gm >> 6, bb = gm & 63;
                    size_t pidx = (size_t)(bb>>4)*16384 + (size_t)(gn>>3)*128
                                + (size_t)(bb&15)*8 + (gn&7);
                    size_t aslab = (size_t)(srcOff + srcStep * (2*kd + 1));
                    float add = (float)Src[aslab*65536 + pidx];
                    size_t dslab = (size_t)(dstOff + dstStep * kd);
                    Dst[dslab*65536 + pidx] = (f16)(acc[i][j][r] + add);
                }
            }
    } else {
        // ---------------- sq body ----------------
        f16 (*As2)[40] = (f16(*)[40])pool;             // 10240 B
        f16 (*Bs2)[40] = (f16(*)[40])(pool + 10240);   // 10240 B
        int m0 = (blockIdx.x - nx) * 128;

        for (int kt = 0; kt < 32; ++kt) {
            __syncthreads();
            #pragma unroll
            for (int c = t; c < 512; c += 256) {       // A rows m, k-contig
                int row = c >> 2, q = c & 3;
                *reinterpret_cast<float4*>(&As2[row][q*8]) =
                    *reinterpret_cast<const float4*>(P + (size_t)(m0+row)*1024 + kt*32 + q*8);
            }
            #pragma unroll
            for (int c = t; c < 512; c += 256) {       // Bs[n][k] = P[k][n0+n]
                int r = c >> 4, q = c & 15;
                f16x8 v = *reinterpret_cast<const f16x8*>(P + (size_t)(kt*32 + r)*1024 + n0 + q*8);
                #pragma unroll
                for (int e = 0; e < 8; ++e) Bs2[q*8+e][r] = v[e];
            }
            __syncthreads();

            f16x8 af[4], bf[4];
            #pragma unroll
            for (int i = 0; i < 4; i++)
                af[i] = *reinterpret_cast<const f16x8*>(&As2[64*wm + 16*i + lm][8*lh]);
            #pragma unroll
            for (int j = 0; j < 4; j++)
                bf[j] = *reinterpret_cast<const f16x8*>(&Bs2[64*wn + 16*j + lm][8*lh]);
            #pragma unroll
            for (int i = 0; i < 4; i++)
                #pragma unroll
                for (int j = 0; j < 4; j++)
                    acc[i][j] = __builtin_amdgcn_mfma_f32_16x16x32_f16(af[i], bf[j], acc[i][j], 0, 0, 0);
        }

        int r0 = lh * 4;
        #pragma unroll
        for (int i = 0; i < 4; i++)
            #pragma unroll
            for (int j = 0; j < 4; j++) {
                int gmb = m0 + 64*wm + 16*i + r0;
                int gn  = n0 + 64*wn + 16*j + lm;
                #pragma unroll
                for (int r = 0; r < 4; r++)
                    Pout[(size_t)(gmb+r)*1024 + gn] = (f16)acc[i][j][r];
            }
    }
}

// ---------- flag-sync recurrence kernel (r13-verified: pipeline + fence-free publish) ----------
// mode 1 (CHAIN): 64 WGs, nch=1. step t: Hs[16t] -> Hs[16t+16], u = Hs[16t+8] (v4).
//   decode: r=wg&7, s=wg>>3: g=bg=r>>1, cg=((r&1)<<3)|s, p=0  (group on XCD pair)
// mode 2 (FILL): 256 WGs, nch=8. step t: Hs[c*16+t] -> +1, u = Xh[c*16+t], c=p*8+i.
//   decode: r=wg&7, s=wg>>3: g=2r+(s>>4), cg=s&15, p=g>>2, bg=g&3 (group on one XCD)
// Fill is passed flags+512 (disjoint bank) so no mid-stream flag reset is needed.
__global__ void __launch_bounds__(256) __attribute__((amdgpu_waves_per_eu(1, 1)))
k_chain(
    const f16* __restrict__ W,        // [1024][1024] row-major (A or A16)
    const f16* __restrict__ U,        // u base (slab-packed)
    f16* __restrict__ Hs,
    unsigned int* __restrict__ flags,
    int nstep, int mode, int nch)
{
    int wg = blockIdx.x;
    int r_ = wg & 7, s_ = wg >> 3;
    int g, cg, p, bg;
    if (mode == 1) { g = r_ >> 1; cg = ((r_ & 1) << 3) | s_; p = 0;       bg = g;     }
    else           { g = 2*r_ + (s_ >> 4); cg = s_ & 15;     p = g >> 2;  bg = g & 3; }
    int w  = threadIdx.x >> 6;
    int l  = threadIdx.x & 63;
    int lm = l & 15, lh = l >> 4;
    int ccol = cg * 64 + w * 16 + lm;

    __shared__ f16 hbuf[2][16384];      // 64 KB double-buffered h slab
    __shared__ float lt[4][16][17];

    // register-resident recurrent weights: 16 cols x K=1024 = 128 VGPRs/lane.
    f16x8 bw[32];
    #pragma unroll
    for (int kt = 0; kt < 32; ++kt)
        bw[kt] = *reinterpret_cast<const f16x8*>(W + (size_t)ccol * 1024 + kt*32 + lh*8);
    #pragma unroll
    for (int kt = 0; kt < 32; ++kt)
        asm volatile("" : "+v"(bw[kt]));

    const int flagBase = g * 16;
    int b_ep = l & 15, cb_ep = l >> 4;
    int cblk = cg*8 + w*2 + cb_ep;

    for (int t = 0; t < nstep; ++t) {
        if (t > 0) {
            if (threadIdx.x < 16) {
                unsigned int tgt = (unsigned int)t;
                const unsigned int* fp = &flags[(flagBase + (int)threadIdx.x) * 8];
                while (__hip_atomic_load(fp, __ATOMIC_RELAXED, __HIP_MEMORY_SCOPE_AGENT) < tgt)
                    __builtin_amdgcn_s_sleep(1);
            }
            __syncthreads();
            asm volatile("" ::: "memory");
        }

        auto slabs = [&](int i, size_t& rS, size_t& wS, size_t& uS) {
            if (mode == 1) { rS = (size_t)(16*t); wS = rS + 16; uS = rS + 8; }
            else { int c = p*nch + i; rS = (size_t)(c*16 + t); wS = rS + 1; uS = rS; }
        };
        auto STAGE = [&](size_t rS, int buf) {
            const char* gsrc = (const char*)Hs + (rS*65536 + (size_t)bg*16384)*2
                             + (size_t)w*8192 + (size_t)l*16;
            char* ldst = (char*)&hbuf[buf][0] + (size_t)w*8192;
            #pragma unroll
            for (int q = 0; q < 8; ++q)
                __builtin_amdgcn_global_load_lds(
                    (const __attribute__((address_space(1))) void*)(gsrc + q*1024),
                    (__attribute__((address_space(3))) void*)(ldst + q*1024),
                    16, 0, 0);
        };
        auto XV = [&](size_t uS) -> f16x8 {
            f16x8 v = {};
            if (l < 32)
                v = *reinterpret_cast<const f16x8*>(
                    U + uS*65536 + (size_t)bg*16384 + (size_t)cblk*128 + b_ep*8);
            return v;
        };

        // prologue: chunk 0 -> buf 0 (9 memops/wave)
        f16x8 xv0, xv1;
        {
            size_t rS, wS, uS; slabs(0, rS, wS, uS);
            STAGE(rS, 0);
            xv0 = XV(uS);
        }

        for (int i = 0; i < nch; ++i) {
            int nxt = i + 1;
            if (nxt < nch) {
                size_t rS, wS, uS; slabs(nxt, rS, wS, uS);
                STAGE(rS, nxt & 1);
                if (nxt & 1) xv1 = XV(uS); else xv0 = XV(uS);
                asm volatile("s_waitcnt vmcnt(9)" ::: "memory");
            } else {
                asm volatile("s_waitcnt vmcnt(0)" ::: "memory");
            }
            __syncthreads();

            const f16* cbuf = &hbuf[i & 1][0];
            f32x4 a0 = (f32x4){0.f,0.f,0.f,0.f};
            f32x4 a1 = (f32x4){0.f,0.f,0.f,0.f};
            #pragma unroll
            for (int kt = 0; kt < 32; ++kt) {
                f16x8 af = *reinterpret_cast<const f16x8*>(&cbuf[(size_t)(kt*4 + lh)*128 + lm*8]);
                if (kt & 1) a1 = __builtin_amdgcn_mfma_f32_16x16x32_f16(af, bw[kt], a1, 0, 0, 0);
                else        a0 = __builtin_amdgcn_mfma_f32_16x16x32_f16(af, bw[kt], a0, 0, 0, 0);
            }
            f32x4 acc = a0 + a1;

            #pragma unroll
            for (int r = 0; r < 4; ++r)
                lt[w][lh*4 + r][lm] = acc[r];
            // wave-private RAW through LDS (compiler inserts lgkmcnt)

            if (l < 32) {
                f16x8 xvc = (i & 1) ? xv1 : xv0;
                size_t rS, wS, uS; slabs(i, rS, wS, uS);
                f16x8 hv;
                #pragma unroll
                for (int e = 0; e < 8; ++e)
                    hv[e] = (f16)(lt[w][b_ep][cb_ep*8 + e] + (float)xvc[e]);
                f16* dst = Hs + wS*65536 + (size_t)bg*16384 + (size_t)cblk*128 + b_ep*8;
                i32x4 iv = __builtin_bit_cast(i32x4, hv);
                asm volatile("global_store_dwordx4 %0, %1, off sc0 sc1"
                             :: "v"(dst), "v"(iv) : "memory");
            }
            __syncthreads();   // all waves done reading buf[i&1] before it is restaged
        }

        asm volatile("s_waitcnt vmcnt(0)" ::: "memory");
        __syncthreads();
        if (threadIdx.x == 0) {
            unsigned int* fp = &flags[(flagBase + cg)*8];
            unsigned int val = (unsigned int)(t + 1);
            asm volatile("global_store_dword %0, %1, off sc0 sc1"
                         :: "v"(fp), "v"(val) : "memory");
        }
    }
}

// ---------- phase 3: output GEMM  Out += Hs @ Wro^T (verified r11) ----------
__global__ __launch_bounds__(256) void k_gemm2(
    const f16* __restrict__ Hs, const f16* __restrict__ Bm, float* __restrict__ Out)
{
    __shared__ f16 As[4096];   // 8 KB: [ttloc2][bg4][kblk4][b16][e8]
    __shared__ f16 Bs[128*32]; // 8 KB
    int m0 = blockIdx.x * 128;          // m' = t*64 + b
    int n0 = blockIdx.y * 128;
    int t = threadIdx.x;
    int l = t & 63, w = t >> 6;
    int wm = w >> 1, wn = w & 1;
    int lm = l & 15, lh = l >> 4;

    f32x4 acc[4][4];
    #pragma unroll
    for (int i = 0; i < 4; i++)
        #pragma unroll
        for (int j = 0; j < 4; j++) acc[i][j] = (f32x4){0.f,0.f,0.f,0.f};

    const size_t lgo = (size_t)(l >> 2) * 2048 + (size_t)(l & 3) * 16;
    const int tt0 = m0 >> 6;

    for (int kt = 0; kt < 32; ++kt) {
        __syncthreads();
        {
            #pragma unroll
            for (int j = 0; j < 2; ++j) {
                int ch  = w*2 + j;               // 0..7
                int ttl = ch >> 2, bgc = ch & 3;
                const char* gsrc = (const char*)(Hs + (size_t)(tt0 + ttl)*65536
                                    + (size_t)bgc*16384 + (size_t)kt*512) + (size_t)l*16;
                __builtin_amdgcn_global_load_lds(
                    (const __attribute__((address_space(1))) void*)gsrc,
                    (__attribute__((address_space(3))) void*)((char*)As + ch*1024), 16, 0, 0);
            }
            const char* gb = (const char*)(Bm + (size_t)(n0 + w*32) * 1024 + kt*32);
            char* lb = (char*)Bs + w * 2048;
            #pragma unroll
            for (int j = 0; j < 2; ++j)
                __builtin_amdgcn_global_load_lds(
                    (const __attribute__((address_space(1))) void*)(gb + (size_t)j*32768 + lgo),
                    (__attribute__((address_space(3))) void*)(lb + j*1024), 16, 0, 0);
        }
        asm volatile("s_waitcnt vmcnt(0)" ::: "memory");
        __syncthreads();

        f16x8 af[4], bf[4];
        #pragma unroll
        for (int i = 0; i < 4; i++)
            af[i] = *reinterpret_cast<const f16x8*>(As + wm*2048 + i*512 + lh*128 + lm*8);
        #pragma unroll
        for (int j = 0; j < 4; j++)
            bf[j] = *reinterpret_cast<const f16x8*>(Bs + (64*wn + 16*j + lm)*32 + 8*lh);
        #pragma unroll
        for (int i = 0; i < 4; i++)
            #pragma unroll
            for (int j = 0; j < 4; j++)
                acc[i][j] = __builtin_amdgcn_mfma_f32_16x16x32_f16(af[i], bf[j], acc[i][j], 0, 0, 0);
    }

    int r0 = lh * 4;
    #pragma unroll
    for (int i = 0; i < 4; i++)
        #pragma unroll
        for (int j = 0; j < 4; j++) {
            int gmb = m0 + 64*wm + 16*i + r0;
            int gn  = n0 + 64*wn + 16*j + lm;
            #pragma unroll
            for (int r = 0; r < 4; r++) {
                int gm = gmb + r;               // m' = t*64 + b
                int bb = gm & 63, tt = gm >> 6;
                size_t o = ((size_t)bb*512 + tt)*1024 + gn;
                Out[o] += acc[i][j][r];
            }
        }
}

// ---------- workspace layout (bytes) — 136.09 MB total ----------
// [0, 4M)      Wx (gemm1); afterwards Pa @0, Pb @2M (A-power ping-pong)
// [4M, 8M)     Wr  (rows 0..1023 = A = Wrh, rows 1024..2047 = Wro)
// [8M, 72M)    Xh  [512 slabs]
// [72M, 136M)  Hs  [512 slabs]; ALSO Xf f16 [32768][1024] pre-gemm1 (dead after);
//              then V1 -> slabs 1..256, V2 -> odd 257.., V3 -> 2+4m, V4 -> 8+16m
// [136M, +16K) flags u32[4096]: chain bank [0,512), fill bank [512,2560)

extern "C" void kernel_launch(void* const* d_in, const int* in_sizes, int n_in,
                              void* d_out, int out_size, void* d_ws, size_t ws_size,
                              hipStream_t stream) {
    const float* X  = (const float*)d_in[0];
    const float* H0 = (const float*)d_in[1];
    const float* Wh = (const float*)d_in[2];
    const float* bh = (const float*)d_in[3];
    const float* Wo = (const float*)d_in[4];
    const float* bo = (const float*)d_in[5];
    float* Out = (float*)d_out;

    char* ws = (char*)d_ws;
    f16* Wx = (f16*)(ws);
    f16* Pa = (f16*)(ws);                               // aliases Wx (dead after gemm1)
    f16* Pb = (f16*)(ws + (size_t)2*1024*1024);
    f16* Wr = (f16*)(ws + (size_t)4*1024*1024);
    f16* Xh = (f16*)(ws + (size_t)8*1024*1024);
    f16* Hs = (f16*)(ws + (size_t)8*1024*1024 + (size_t)M_TOT*1024*2);
    f16* Xf = Hs;                                       // aliases Hs (dead until after gemm1)
    unsigned int* flags = (unsigned int*)(ws + (size_t)8*1024*1024 + (size_t)2*M_TOT*1024*2);

    hipLaunchKernelGGL(k_prep, dim3(16384 + 2048), dim3(256), 0, stream, Wh, Wo, X, Wx, Wr, Xf);
    hipLaunchKernelGGL(k_gemm1, dim3(256, 16), dim3(256), 0, stream, Xf, Wx, bh, bo, Xh, Out);
    hipLaunchKernelGGL(k_init, dim3(48), dim3(256), 0, stream, H0, Hs, flags);  // after gemm1: Xf dead

    // fused tree: each dispatch = vlevel (nx x 8 blocks) + squaring (8 x 8 blocks)
    hipLaunchKernelGGL(k_tree, dim3(128+8, 8), dim3(256), 0, stream, Wr, Xh, Hs, 0,1, 1,1,   128, Wr, Pa); // V1 + A2
    hipLaunchKernelGGL(k_tree, dim3(64+8, 8),  dim3(256), 0, stream, Pa, Hs, Hs, 1,1, 257,2,  64, Pa, Pb); // V2 + A4
    hipLaunchKernelGGL(k_tree, dim3(32+8, 8),  dim3(256), 0, stream, Pb, Hs, Hs, 257,2, 2,4,  32, Pb, Pa); // V3 + A8
    hipLaunchKernelGGL(k_tree, dim3(16+8, 8),  dim3(256), 0, stream, Pa, Hs, Hs, 2,4, 8,16,   16, Pa, Pb); // V4 + A16

    // chain: h_{16(t+1)} = A16 h_{16t} + v4_t   (31 steps, 64 WGs, flag bank 0)
    {
        int nstep = 31, mode = 1, nch = 1;
        void* args[] = { (void*)&Pb, (void*)&Hs, (void*)&Hs, (void*)&flags,
                         (void*)&nstep, (void*)&mode, (void*)&nch };
        if (hipLaunchCooperativeKernel((const void*)k_chain, dim3(64), dim3(256),
                                       args, 0, stream) != hipSuccess) {
            hipLaunchKernelGGL(k_chain, dim3(64), dim3(256), 0, stream,
                               Pb, Hs, Hs, flags, 31, 1, 1);
        }
    }

    // fill: h_{c*16+t+1} = A h_{c*16+t} + u   (15 steps, 256 WGs x nch=8, flag bank 512)
    {
        unsigned int* flags2 = flags + 512;
        int nstep = 15, mode = 2, nch = 8;
        void* args[] = { (void*)&Wr, (void*)&Xh, (void*)&Hs, (void*)&flags2,
                         (void*)&nstep, (void*)&mode, (void*)&nch };
        if (hipLaunchCooperativeKernel((const void*)k_chain, dim3(256), dim3(256),
                                       args, 0, stream) != hipSuccess) {
            hipLaunchKernelGGL(k_chain, dim3(256), dim3(256), 0, stream,
                               Wr, Xh, Hs, flags2, 15, 2, 8);
        }
    }

    f16* Wro = Wr + (size_t)1024*1024;
    hipLaunchKernelGGL(k_gemm2, dim3(256, 8), dim3(256), 0, stream, Hs, Wro, Out);
}

// Round 15
// 980.947 us; speedup vs baseline: 1.1524x; 1.0356x over previous
//
#include <hip/hip_runtime.h>
#include <hip/hip_bf16.h>

// RNNLayer: B=64, T=512, D_IN=D_H=D_OUT=1024.
// h_{t+1} = A h_t + u_t  (A = Wrh, u_t = x_t@Wxh^T + bh);  o_t = x_t@Wxo^T + h_t@Wro^T + bo
// Scan decomposition (sequential depth 511 -> 31 + 15):
//   tree:  v1=A u+u', v2=A2 v1+v1', v3=A4 v2+v2', v4=A8 v3+v3'  (4 fused GEMM dispatches)
//   chain: h_{16(k+1)} = A16 h_{16k} + v4_k       (31 flag-sync steps, 64 WGs)
//   fill:  h_{16k+tau+1} = A h_{16k+tau} + u      (15 flag-sync steps, 256 WGs, nch=8)
// r14 -> r15: grid-axis swap for A-panel locality (FETCH 245 MB vs 68 MB ideal
// showed 3.5x A re-fetch). gemm1/gemm2/tree grids become (n-tiles, m-tiles):
// the co-dispatched x-group shares ONE A-panel; small B matrices (4 MB / 2 MB)
// turn L2-resident. Kernel bodies unchanged except the m0/n0 index lines.

typedef _Float16 f16;
typedef _Float16 f16x8 __attribute__((ext_vector_type(8)));
typedef _Float16 f16x4 __attribute__((ext_vector_type(4)));
typedef float f32x4 __attribute__((ext_vector_type(4)));
typedef int i32x4 __attribute__((ext_vector_type(4)));

#define T_LEN 512
#define BATCH 64
#define M_TOT (BATCH * T_LEN)   // 32768

// slab layout (per t): [bg 4][cblk 128][b 16][8] f16 = 65536 elems (128 KB)

// ---------- prep: stacked fp16 weights + X f32->f16 (fused) ----------
__global__ void k_prep(const float* __restrict__ Wh, const float* __restrict__ Wo,
                       const float* __restrict__ X,
                       f16* __restrict__ Wx, f16* __restrict__ Wr, f16* __restrict__ Xf) {
    int bid = blockIdx.x;
    if (bid < 16384) {
        size_t i = ((size_t)bid * 256 + threadIdx.x) * 8;
        float4 a = *reinterpret_cast<const float4*>(X + i);
        float4 b = *reinterpret_cast<const float4*>(X + i + 4);
        f16x8 v;
        v[0]=(f16)a.x; v[1]=(f16)a.y; v[2]=(f16)a.z; v[3]=(f16)a.w;
        v[4]=(f16)b.x; v[5]=(f16)b.y; v[6]=(f16)b.z; v[7]=(f16)b.w;
        *reinterpret_cast<f16x8*>(Xf + i) = v;
    } else {
        int n = bid - 16384;             // 0..2047
        int t4 = threadIdx.x * 4;        // 0..1020
        const float* src = (n < 1024) ? (Wh + (size_t)n * 2048)
                                      : (Wo + (size_t)(n - 1024) * 2048);
        float4 a = *reinterpret_cast<const float4*>(src + t4);
        float4 b = *reinterpret_cast<const float4*>(src + 1024 + t4);
        f16x4 va, vb;
        va[0]=(f16)a.x; va[1]=(f16)a.y; va[2]=(f16)a.z; va[3]=(f16)a.w;
        vb[0]=(f16)b.x; vb[1]=(f16)b.y; vb[2]=(f16)b.z; vb[3]=(f16)b.w;
        *reinterpret_cast<f16x4*>(Wx + (size_t)n*1024 + t4) = va;
        *reinterpret_cast<f16x4*>(Wr + (size_t)n*1024 + t4) = vb;
    }
}

// ---------- init: Hs[0] from H0 (packed) + zero both flag banks (fused) ----------
__global__ void k_init(const float* __restrict__ H0, f16* __restrict__ Hs,
                       unsigned int* __restrict__ flags) {
    int bid = blockIdx.x;
    if (bid < 32) {
        int tid = bid * 256 + threadIdx.x;   // 8192
        int b = tid >> 7, kb = tid & 127;
        float4 x0 = *reinterpret_cast<const float4*>(H0 + (size_t)b*1024 + kb*8);
        float4 x1 = *reinterpret_cast<const float4*>(H0 + (size_t)b*1024 + kb*8 + 4);
        f16x8 v;
        v[0]=(f16)x0.x; v[1]=(f16)x0.y; v[2]=(f16)x0.z; v[3]=(f16)x0.w;
        v[4]=(f16)x1.x; v[5]=(f16)x1.y; v[6]=(f16)x1.z; v[7]=(f16)x1.w;
        size_t idx = (size_t)(b >> 4)*16384 + (size_t)kb*128 + (size_t)(b & 15)*8;
        *reinterpret_cast<f16x8*>(Hs + idx) = v;
    } else {
        flags[(bid - 32) * 256 + threadIdx.x] = 0;   // 16 blocks -> 4096 u32 (16 KB)
    }
}

// ---------- phase 1: input projection GEMM (m97 structure, BK=32) ----------
// grid (16 n-tiles, 256 m-tiles): x-group shares one A-panel; B L2-resident.
__global__ __launch_bounds__(256) void k_gemm1(
    const f16* __restrict__ Af, const f16* __restrict__ Bm,
    const float* __restrict__ bh, const float* __restrict__ bo,
    f16* __restrict__ Xh, float* __restrict__ Out)
{
    __shared__ f16 As[128*32];   // 8 KB, linear row-major [128][32]
    __shared__ f16 Bs[128*32];   // 8 KB
    int m0 = blockIdx.y * 128;
    int n0 = blockIdx.x * 128;
    int t = threadIdx.x;
    int l = t & 63, w = t >> 6;
    int wm = w >> 1, wn = w & 1;
    int lm = l & 15, lh = l >> 4;

    f32x4 acc[4][4];
    #pragma unroll
    for (int i = 0; i < 4; i++)
        #pragma unroll
        for (int j = 0; j < 4; j++) acc[i][j] = (f32x4){0.f,0.f,0.f,0.f};

    const size_t lgo = (size_t)(l >> 2) * 2048 + (size_t)(l & 3) * 16;

    for (int kt = 0; kt < 32; ++kt) {
        __syncthreads();
        {
            const char* ga = (const char*)(Af + (size_t)(m0 + w*32) * 1024 + kt*32);
            const char* gb = (const char*)(Bm + (size_t)(n0 + w*32) * 1024 + kt*32);
            char* la = (char*)As + w * 2048;
            char* lb = (char*)Bs + w * 2048;
            #pragma unroll
            for (int j = 0; j < 2; ++j) {
                __builtin_amdgcn_global_load_lds(
                    (const __attribute__((address_space(1))) void*)(ga + (size_t)j*32768 + lgo),
                    (__attribute__((address_space(3))) void*)(la + j*1024), 16, 0, 0);
                __builtin_amdgcn_global_load_lds(
                    (const __attribute__((address_space(1))) void*)(gb + (size_t)j*32768 + lgo),
                    (__attribute__((address_space(3))) void*)(lb + j*1024), 16, 0, 0);
            }
        }
        asm volatile("s_waitcnt vmcnt(0)" ::: "memory");
        __syncthreads();

        f16x8 af[4], bf[4];
        #pragma unroll
        for (int i = 0; i < 4; i++)
            af[i] = *reinterpret_cast<const f16x8*>(As + (64*wm + 16*i + lm)*32 + 8*lh);
        #pragma unroll
        for (int j = 0; j < 4; j++)
            bf[j] = *reinterpret_cast<const f16x8*>(Bs + (64*wn + 16*j + lm)*32 + 8*lh);
        #pragma unroll
        for (int i = 0; i < 4; i++)
            #pragma unroll
            for (int j = 0; j < 4; j++)
                acc[i][j] = __builtin_amdgcn_mfma_f32_16x16x32_f16(af[i], bf[j], acc[i][j], 0, 0, 0);
    }

    int r0 = lh * 4;
    bool isH = (n0 < 1024);
    #pragma unroll
    for (int i = 0; i < 4; i++)
        #pragma unroll
        for (int j = 0; j < 4; j++) {
            int gmb = m0 + 64*wm + 16*i + r0;
            int gn  = n0 + 64*wn + 16*j + lm;
            #pragma unroll
            for (int r = 0; r < 4; r++) {
                float v = acc[i][j][r];
                int gm = gmb + r;                 // m = b*512 + t
                if (isH) {
                    int tt = gm & 511, bb = gm >> 9;
                    size_t idx = (size_t)tt*65536 + (size_t)(bb>>4)*16384
                               + (size_t)(gn>>3)*128 + (size_t)(bb&15)*8 + (gn&7);
                    Xh[idx] = (f16)(v + bh[gn]);
                } else {
                    Out[(size_t)gm*1024 + (gn - 1024)] = v + bo[gn - 1024];
                }
            }
        }
}

// ---------- fused tree dispatch: vlevel (blockIdx.x < 8) + matrix squaring ----------
// grid (16, nx): x<8 -> vlevel {n0=x*128, m0=y*128}; x>=8 -> sq {n0=(x-8)*128,
// m0=y*128, exit if y>=8}. All writes within one dispatch disjoint (audited r14).
__global__ __launch_bounds__(256) void k_tree(
    const f16* __restrict__ M, const f16* __restrict__ Src, f16* __restrict__ Dst,
    int srcOff, int srcStep, int dstOff, int dstStep, int nx,
    const f16* __restrict__ P, f16* __restrict__ Pout)
{
    __shared__ __align__(16) char pool[20480];
    int t = threadIdx.x;
    int l = t & 63, w = t >> 6;
    int wm = w >> 1, wn = w & 1;
    int lm = l & 15, lh = l >> 4;

    f32x4 acc[4][4];
    #pragma unroll
    for (int i = 0; i < 4; i++)
        #pragma unroll
        for (int j = 0; j < 4; j++) acc[i][j] = (f32x4){0.f,0.f,0.f,0.f};

    if (blockIdx.x < 8) {
        // ---------------- vlevel body ----------------
        f16* As = (f16*)pool;            // 8 KB: [kdl2][bg4][kblk4][b16][e8]
        f16* Bs = (f16*)(pool + 8192);   // 8 KB: [row][32] linear
        int m0 = blockIdx.y * 128;
        int n0 = blockIdx.x * 128;
        const size_t lgo = (size_t)(l >> 2) * 2048 + (size_t)(l & 3) * 16;
        const int kd0 = m0 >> 6;

        for (int kt = 0; kt < 32; ++kt) {
            __syncthreads();
            {
                #pragma unroll
                for (int j = 0; j < 2; ++j) {
                    int ch  = w*2 + j;               // 0..7
                    int kdl = ch >> 2, bgc = ch & 3;
                    size_t slab = (size_t)(srcOff + srcStep * (2*(kd0 + kdl)));
                    const char* gsrc = (const char*)(Src + slab*65536
                                        + (size_t)bgc*16384 + (size_t)kt*512) + (size_t)l*16;
                    __builtin_amdgcn_global_load_lds(
                        (const __attribute__((address_space(1))) void*)gsrc,
                        (__attribute__((address_space(3))) void*)((char*)As + ch*1024), 16, 0, 0);
                }
                const char* gb = (const char*)(M + (size_t)(n0 + w*32) * 1024 + kt*32);
                char* lb = (char*)Bs + w * 2048;
                #pragma unroll
                for (int j = 0; j < 2; ++j)
                    __builtin_amdgcn_global_load_lds(
                        (const __attribute__((address_space(1))) void*)(gb + (size_t)j*32768 + lgo),
                        (__attribute__((address_space(3))) void*)(lb + j*1024), 16, 0, 0);
            }
            asm volatile("s_waitcnt vmcnt(0)" ::: "memory");
            __syncthreads();

            f16x8 af[4], bf[4];
            #pragma unroll
            for (int i = 0; i < 4; i++)
                af[i] = *reinterpret_cast<const f16x8*>(As + wm*2048 + i*512 + lh*128 + lm*8);
            #pragma unroll
            for (int j = 0; j < 4; j++)
                bf[j] = *reinterpret_cast<const f16x8*>(Bs + (64*wn + 16*j + lm)*32 + 8*lh);
            #pragma unroll
            for (int i = 0; i < 4; i++)
                #pragma unroll
                for (int j = 0; j < 4; j++)
                    acc[i][j] = __builtin_amdgcn_mfma_f32_16x16x32_f16(af[i], bf[j], acc[i][j], 0, 0, 0);
        }

        int r0 = lh * 4;
        #pragma unroll
        for (int i = 0; i < 4; i++)
            #pragma unroll
            for (int j = 0; j < 4; j++) {
                int gmb = m0 + 64*wm + 16*i + r0;
                int gn  = n0 + 64*wn + 16*j + lm;
                #pragma unroll
                for (int r = 0; r < 4; r++) {
                    int gm = gmb + r;
                    int kd = gm >> 6, bb = gm & 63;
                    size_t pidx = (size_t)(bb>>4)*16384 + (size_t)(gn>>3)*128
                                + (size_t)(bb&15)*8 + (gn&7);
                    size_t aslab = (size_t)(srcOff + srcStep * (2*kd + 1));
                    float add = (float)Src[aslab*65536 + pidx];
                    size_t dslab = (size_t)(dstOff + dstStep * kd);
                    Dst[dslab*65536 + pidx] = (f16)(acc[i][j][r] + add);
                }
            }
    } else {
        // ---------------- sq body ----------------
        if (blockIdx.y >= 8) return;
        f16 (*As2)[40] = (f16(*)[40])pool;             // 10240 B
        f16 (*Bs2)[40] = (f16(*)[40])(pool + 10240);   // 10240 B
        int m0 = blockIdx.y * 128;
        int n0 = (blockIdx.x - 8) * 128;

        for (int kt = 0; kt < 32; ++kt) {
            __syncthreads();
            #pragma unroll
            for (int c = t; c < 512; c += 256) {       // A rows m, k-contig
                int row = c >> 2, q = c & 3;
                *reinterpret_cast<float4*>(&As2[row][q*8]) =
                    *reinterpret_cast<const float4*>(P + (size_t)(m0+row)*1024 + kt*32 + q*8);
            }
            #pragma unroll
            for (int c = t; c < 512; c += 256) {       // Bs[n][k] = P[k][n0+n]
                int r = c >> 4, q = c & 15;
                f16x8 v = *reinterpret_cast<const f16x8*>(P + (size_t)(kt*32 + r)*1024 + n0 + q*8);
                #pragma unroll
                for (int e = 0; e < 8; ++e) Bs2[q*8+e][r] = v[e];
            }
            __syncthreads();

            f16x8 af[4], bf[4];
            #pragma unroll
            for (int i = 0; i < 4; i++)
                af[i] = *reinterpret_cast<const f16x8*>(&As2[64*wm + 16*i + lm][8*lh]);
            #pragma unroll
            for (int j = 0; j < 4; j++)
                bf[j] = *reinterpret_cast<const f16x8*>(&Bs2[64*wn + 16*j + lm][8*lh]);
            #pragma unroll
            for (int i = 0; i < 4; i++)
                #pragma unroll
                for (int j = 0; j < 4; j++)
                    acc[i][j] = __builtin_amdgcn_mfma_f32_16x16x32_f16(af[i], bf[j], acc[i][j], 0, 0, 0);
        }

        int r0 = lh * 4;
        #pragma unroll
        for (int i = 0; i < 4; i++)
            #pragma unroll
            for (int j = 0; j < 4; j++) {
                int gmb = m0 + 64*wm + 16*i + r0;
                int gn  = n0 + 64*wn + 16*j + lm;
                #pragma unroll
                for (int r = 0; r < 4; r++)
                    Pout[(size_t)(gmb+r)*1024 + gn] = (f16)acc[i][j][r];
            }
    }
}

// ---------- flag-sync recurrence kernel (r13-verified: pipeline + fence-free publish) ----------
// mode 1 (CHAIN): 64 WGs, nch=1. step t: Hs[16t] -> Hs[16t+16], u = Hs[16t+8] (v4).
//   decode: r=wg&7, s=wg>>3: g=bg=r>>1, cg=((r&1)<<3)|s, p=0  (group on XCD pair)
// mode 2 (FILL): 256 WGs, nch=8. step t: Hs[c*16+t] -> +1, u = Xh[c*16+t], c=p*8+i.
//   decode: r=wg&7, s=wg>>3: g=2r+(s>>4), cg=s&15, p=g>>2, bg=g&3 (group on one XCD)
// Fill is passed flags+512 (disjoint bank) so no mid-stream flag reset is needed.
__global__ void __launch_bounds__(256) __attribute__((amdgpu_waves_per_eu(1, 1)))
k_chain(
    const f16* __restrict__ W,        // [1024][1024] row-major (A or A16)
    const f16* __restrict__ U,        // u base (slab-packed)
    f16* __restrict__ Hs,
    unsigned int* __restrict__ flags,
    int nstep, int mode, int nch)
{
    int wg = blockIdx.x;
    int r_ = wg & 7, s_ = wg >> 3;
    int g, cg, p, bg;
    if (mode == 1) { g = r_ >> 1; cg = ((r_ & 1) << 3) | s_; p = 0;       bg = g;     }
    else           { g = 2*r_ + (s_ >> 4); cg = s_ & 15;     p = g >> 2;  bg = g & 3; }
    int w  = threadIdx.x >> 6;
    int l  = threadIdx.x & 63;
    int lm = l & 15, lh = l >> 4;
    int ccol = cg * 64 + w * 16 + lm;

    __shared__ f16 hbuf[2][16384];      // 64 KB double-buffered h slab
    __shared__ float lt[4][16][17];

    // register-resident recurrent weights: 16 cols x K=1024 = 128 VGPRs/lane.
    f16x8 bw[32];
    #pragma unroll
    for (int kt = 0; kt < 32; ++kt)
        bw[kt] = *reinterpret_cast<const f16x8*>(W + (size_t)ccol * 1024 + kt*32 + lh*8);
    #pragma unroll
    for (int kt = 0; kt < 32; ++kt)
        asm volatile("" : "+v"(bw[kt]));

    const int flagBase = g * 16;
    int b_ep = l & 15, cb_ep = l >> 4;
    int cblk = cg*8 + w*2 + cb_ep;

    for (int t = 0; t < nstep; ++t) {
        if (t > 0) {
            if (threadIdx.x < 16) {
                unsigned int tgt = (unsigned int)t;
                const unsigned int* fp = &flags[(flagBase + (int)threadIdx.x) * 8];
                while (__hip_atomic_load(fp, __ATOMIC_RELAXED, __HIP_MEMORY_SCOPE_AGENT) < tgt)
                    __builtin_amdgcn_s_sleep(1);
            }
            __syncthreads();
            asm volatile("" ::: "memory");
        }

        auto slabs = [&](int i, size_t& rS, size_t& wS, size_t& uS) {
            if (mode == 1) { rS = (size_t)(16*t); wS = rS + 16; uS = rS + 8; }
            else { int c = p*nch + i; rS = (size_t)(c*16 + t); wS = rS + 1; uS = rS; }
        };
        auto STAGE = [&](size_t rS, int buf) {
            const char* gsrc = (const char*)Hs + (rS*65536 + (size_t)bg*16384)*2
                             + (size_t)w*8192 + (size_t)l*16;
            char* ldst = (char*)&hbuf[buf][0] + (size_t)w*8192;
            #pragma unroll
            for (int q = 0; q < 8; ++q)
                __builtin_amdgcn_global_load_lds(
                    (const __attribute__((address_space(1))) void*)(gsrc + q*1024),
                    (__attribute__((address_space(3))) void*)(ldst + q*1024),
                    16, 0, 0);
        };
        auto XV = [&](size_t uS) -> f16x8 {
            f16x8 v = {};
            if (l < 32)
                v = *reinterpret_cast<const f16x8*>(
                    U + uS*65536 + (size_t)bg*16384 + (size_t)cblk*128 + b_ep*8);
            return v;
        };

        // prologue: chunk 0 -> buf 0 (9 memops/wave)
        f16x8 xv0, xv1;
        {
            size_t rS, wS, uS; slabs(0, rS, wS, uS);
            STAGE(rS, 0);
            xv0 = XV(uS);
        }

        for (int i = 0; i < nch; ++i) {
            int nxt = i + 1;
            if (nxt < nch) {
                size_t rS, wS, uS; slabs(nxt, rS, wS, uS);
                STAGE(rS, nxt & 1);
                if (nxt & 1) xv1 = XV(uS); else xv0 = XV(uS);
                asm volatile("s_waitcnt vmcnt(9)" ::: "memory");
            } else {
                asm volatile("s_waitcnt vmcnt(0)" ::: "memory");
            }
            __syncthreads();

            const f16* cbuf = &hbuf[i & 1][0];
            f32x4 a0 = (f32x4){0.f,0.f,0.f,0.f};
            f32x4 a1 = (f32x4){0.f,0.f,0.f,0.f};
            #pragma unroll
            for (int kt = 0; kt < 32; ++kt) {
                f16x8 af = *reinterpret_cast<const f16x8*>(&cbuf[(size_t)(kt*4 + lh)*128 + lm*8]);
                if (kt & 1) a1 = __builtin_amdgcn_mfma_f32_16x16x32_f16(af, bw[kt], a1, 0, 0, 0);
                else        a0 = __builtin_amdgcn_mfma_f32_16x16x32_f16(af, bw[kt], a0, 0, 0, 0);
            }
            f32x4 acc = a0 + a1;

            #pragma unroll
            for (int r = 0; r < 4; ++r)
                lt[w][lh*4 + r][lm] = acc[r];
            // wave-private RAW through LDS (compiler inserts lgkmcnt)

            if (l < 32) {
                f16x8 xvc = (i & 1) ? xv1 : xv0;
                size_t rS, wS, uS; slabs(i, rS, wS, uS);
                f16x8 hv;
                #pragma unroll
                for (int e = 0; e < 8; ++e)
                    hv[e] = (f16)(lt[w][b_ep][cb_ep*8 + e] + (float)xvc[e]);
                f16* dst = Hs + wS*65536 + (size_t)bg*16384 + (size_t)cblk*128 + b_ep*8;
                i32x4 iv = __builtin_bit_cast(i32x4, hv);
                asm volatile("global_store_dwordx4 %0, %1, off sc0 sc1"
                             :: "v"(dst), "v"(iv) : "memory");
            }
            __syncthreads();   // all waves done reading buf[i&1] before it is restaged
        }

        asm volatile("s_waitcnt vmcnt(0)" ::: "memory");
        __syncthreads();
        if (threadIdx.x == 0) {
            unsigned int* fp = &flags[(flagBase + cg)*8];
            unsigned int val = (unsigned int)(t + 1);
            asm volatile("global_store_dword %0, %1, off sc0 sc1"
                         :: "v"(fp), "v"(val) : "memory");
        }
    }
}

// ---------- phase 3: output GEMM  Out += Hs @ Wro^T ----------
// grid (8 n-tiles, 256 m-tiles): A-panel shared, B (2 MB) L2-resident.
__global__ __launch_bounds__(256) void k_gemm2(
    const f16* __restrict__ Hs, const f16* __restrict__ Bm, float* __restrict__ Out)
{
    __shared__ f16 As[4096];   // 8 KB: [ttloc2][bg4][kblk4][b16][e8]
    __shared__ f16 Bs[128*32]; // 8 KB
    int m0 = blockIdx.y * 128;          // m' = t*64 + b
    int n0 = blockIdx.x * 128;
    int t = threadIdx.x;
    int l = t & 63, w = t >> 6;
    int wm = w >> 1, wn = w & 1;
    int lm = l & 15, lh = l >> 4;

    f32x4 acc[4][4];
    #pragma unroll
    for (int i = 0; i < 4; i++)
        #pragma unroll
        for (int j = 0; j < 4; j++) acc[i][j] = (f32x4){0.f,0.f,0.f,0.f};

    const size_t lgo = (size_t)(l >> 2) * 2048 + (size_t)(l & 3) * 16;
    const int tt0 = m0 >> 6;

    for (int kt = 0; kt < 32; ++kt) {
        __syncthreads();
        {
            #pragma unroll
            for (int j = 0; j < 2; ++j) {
                int ch  = w*2 + j;               // 0..7
                int ttl = ch >> 2, bgc = ch & 3;
                const char* gsrc = (const char*)(Hs + (size_t)(tt0 + ttl)*65536
                                    + (size_t)bgc*16384 + (size_t)kt*512) + (size_t)l*16;
                __builtin_amdgcn_global_load_lds(
                    (const __attribute__((address_space(1))) void*)gsrc,
                    (__attribute__((address_space(3))) void*)((char*)As + ch*1024), 16, 0, 0);
            }
            const char* gb = (const char*)(Bm + (size_t)(n0 + w*32) * 1024 + kt*32);
            char* lb = (char*)Bs + w * 2048;
            #pragma unroll
            for (int j = 0; j < 2; ++j)
                __builtin_amdgcn_global_load_lds(
                    (const __attribute__((address_space(1))) void*)(gb + (size_t)j*32768 + lgo),
                    (__attribute__((address_space(3))) void*)(lb + j*1024), 16, 0, 0);
        }
        asm volatile("s_waitcnt vmcnt(0)" ::: "memory");
        __syncthreads();

        f16x8 af[4], bf[4];
        #pragma unroll
        for (int i = 0; i < 4; i++)
            af[i] = *reinterpret_cast<const f16x8*>(As + wm*2048 + i*512 + lh*128 + lm*8);
        #pragma unroll
        for (int j = 0; j < 4; j++)
            bf[j] = *reinterpret_cast<const f16x8*>(Bs + (64*wn + 16*j + lm)*32 + 8*lh);
        #pragma unroll
        for (int i = 0; i < 4; i++)
            #pragma unroll
            for (int j = 0; j < 4; j++)
                acc[i][j] = __builtin_amdgcn_mfma_f32_16x16x32_f16(af[i], bf[j], acc[i][j], 0, 0, 0);
    }

    int r0 = lh * 4;
    #pragma unroll
    for (int i = 0; i < 4; i++)
        #pragma unroll
        for (int j = 0; j < 4; j++) {
            int gmb = m0 + 64*wm + 16*i + r0;
            int gn  = n0 + 64*wn + 16*j + lm;
            #pragma unroll
            for (int r = 0; r < 4; r++) {
                int gm = gmb + r;               // m' = t*64 + b
                int bb = gm & 63, tt = gm >> 6;
                size_t o = ((size_t)bb*512 + tt)*1024 + gn;
                Out[o] += acc[i][j][r];
            }
        }
}

// ---------- workspace layout (bytes) — 136.09 MB total ----------
// [0, 4M)      Wx (gemm1); afterwards Pa @0, Pb @2M (A-power ping-pong)
// [4M, 8M)     Wr  (rows 0..1023 = A = Wrh, rows 1024..2047 = Wro)
// [8M, 72M)    Xh  [512 slabs]
// [72M, 136M)  Hs  [512 slabs]; ALSO Xf f16 [32768][1024] pre-gemm1 (dead after);
//              then V1 -> slabs 1..256, V2 -> odd 257.., V3 -> 2+4m, V4 -> 8+16m
// [136M, +16K) flags u32[4096]: chain bank [0,512), fill bank [512,2560)

extern "C" void kernel_launch(void* const* d_in, const int* in_sizes, int n_in,
                              void* d_out, int out_size, void* d_ws, size_t ws_size,
                              hipStream_t stream) {
    const float* X  = (const float*)d_in[0];
    const float* H0 = (const float*)d_in[1];
    const float* Wh = (const float*)d_in[2];
    const float* bh = (const float*)d_in[3];
    const float* Wo = (const float*)d_in[4];
    const float* bo = (const float*)d_in[5];
    float* Out = (float*)d_out;

    char* ws = (char*)d_ws;
    f16* Wx = (f16*)(ws);
    f16* Pa = (f16*)(ws);                               // aliases Wx (dead after gemm1)
    f16* Pb = (f16*)(ws + (size_t)2*1024*1024);
    f16* Wr = (f16*)(ws + (size_t)4*1024*1024);
    f16* Xh = (f16*)(ws + (size_t)8*1024*1024);
    f16* Hs = (f16*)(ws + (size_t)8*1024*1024 + (size_t)M_TOT*1024*2);
    f16* Xf = Hs;                                       // aliases Hs (dead until after gemm1)
    unsigned int* flags = (unsigned int*)(ws + (size_t)8*1024*1024 + (size_t)2*M_TOT*1024*2);

    hipLaunchKernelGGL(k_prep, dim3(16384 + 2048), dim3(256), 0, stream, Wh, Wo, X, Wx, Wr, Xf);
    hipLaunchKernelGGL(k_gemm1, dim3(16, 256), dim3(256), 0, stream, Xf, Wx, bh, bo, Xh, Out);
    hipLaunchKernelGGL(k_init, dim3(48), dim3(256), 0, stream, H0, Hs, flags);  // after gemm1: Xf dead

    // fused tree: each dispatch = vlevel (8 x nx blocks) + squaring (8 x 8)
    hipLaunchKernelGGL(k_tree, dim3(16, 128), dim3(256), 0, stream, Wr, Xh, Hs, 0,1, 1,1,   128, Wr, Pa); // V1 + A2
    hipLaunchKernelGGL(k_tree, dim3(16, 64),  dim3(256), 0, stream, Pa, Hs, Hs, 1,1, 257,2,  64, Pa, Pb); // V2 + A4
    hipLaunchKernelGGL(k_tree, dim3(16, 32),  dim3(256), 0, stream, Pb, Hs, Hs, 257,2, 2,4,  32, Pb, Pa); // V3 + A8
    hipLaunchKernelGGL(k_tree, dim3(16, 16),  dim3(256), 0, stream, Pa, Hs, Hs, 2,4, 8,16,   16, Pa, Pb); // V4 + A16

    // chain: h_{16(t+1)} = A16 h_{16t} + v4_t   (31 steps, 64 WGs, flag bank 0)
    {
        int nstep = 31, mode = 1, nch = 1;
        void* args[] = { (void*)&Pb, (void*)&Hs, (void*)&Hs, (void*)&flags,
                         (void*)&nstep, (void*)&mode, (void*)&nch };
        if (hipLaunchCooperativeKernel((const void*)k_chain, dim3(64), dim3(256),
                                       args, 0, stream) != hipSuccess) {
            hipLaunchKernelGGL(k_chain, dim3(64), dim3(256), 0, stream,
                               Pb, Hs, Hs, flags, 31, 1, 1);
        }
    }

    // fill: h_{c*16+t+1} = A h_{c*16+t} + u   (15 steps, 256 WGs x nch=8, flag bank 512)
    {
        unsigned int* flags2 = flags + 512;
        int nstep = 15, mode = 2, nch = 8;
        void* args[] = { (void*)&Wr, (void*)&Xh, (void*)&Hs, (void*)&flags2,
                         (void*)&nstep, (void*)&mode, (void*)&nch };
        if (hipLaunchCooperativeKernel((const void*)k_chain, dim3(256), dim3(256),
                                       args, 0, stream) != hipSuccess) {
            hipLaunchKernelGGL(k_chain, dim3(256), dim3(256), 0, stream,
                               Wr, Xh, Hs, flags2, 15, 2, 8);
        }
    }

    f16* Wro = Wr + (size_t)1024*1024;
    hipLaunchKernelGGL(k_gemm2, dim3(8, 256), dim3(256), 0, stream, Hs, Wro, Out);
}